// Round 1
// baseline (518.693 us; speedup 1.0000x reference)
//
#include <hip/hip_runtime.h>
#include <hip/hip_bf16.h>

// Problem constants
// B=4, S=1024, D=2048, NH=32, NKV=8, HD=64, HALF=32, N_REP=4
// ROWS = B*S = 4096 ; QKV cols = 2048 + 512 + 512 = 3072

typedef __bf16 bf16x8 __attribute__((ext_vector_type(8)));
typedef float  f32x4  __attribute__((ext_vector_type(4)));

#define DEV static __device__ __forceinline__

DEV unsigned short f2bf(float f) {
  __hip_bfloat16 h = __float2bfloat16(f);
  unsigned short u;
  __builtin_memcpy(&u, &h, 2);
  return u;
}
DEV float bf2f(unsigned short u) {
  unsigned int ui = ((unsigned int)u) << 16;
  float f;
  __builtin_memcpy(&f, &ui, 4);
  return f;
}

typedef const unsigned int __attribute__((address_space(1)))* as1_u32cp;
typedef unsigned int __attribute__((address_space(3)))* as3_u32p;

// async global->LDS, 16B per lane. lds dest must be wave-uniform base; HW adds lane*16.
DEV void load16_lds(const unsigned short* g, unsigned short* l) {
  __builtin_amdgcn_global_load_lds((as1_u32cp)(unsigned long long)g,
                                   (as3_u32p)(unsigned int)(unsigned long long)l,
                                   16, 0, 0);
}

DEV f32x4 mfma16x16(bf16x8 a, bf16x8 b, f32x4 c) {
  return __builtin_amdgcn_mfma_f32_16x16x32_bf16(a, b, c, 0, 0, 0);
}

// ---------------------------------------------------------------- convert x -> bf16
__global__ __launch_bounds__(256) void k_convert_x(const float* __restrict__ x,
                                                   unsigned short* __restrict__ xb, int n) {
  int i = (blockIdx.x * 256 + threadIdx.x) * 4;
  if (i < n) {
    float4 v = *(const float4*)(x + i);
    ushort4 o;
    o.x = f2bf(v.x); o.y = f2bf(v.y); o.z = f2bf(v.z); o.w = f2bf(v.w);
    *(ushort4*)(xb + i) = o;
  }
}

// --------------------------------------------------- transpose fp32 [2048][N] -> bf16 [N][2048]
__global__ __launch_bounds__(256) void k_transpose_w(const float* __restrict__ src,
                                                     unsigned short* __restrict__ dst, int N) {
  __shared__ float t[32][33];
  const int n0 = blockIdx.x * 32, k0 = blockIdx.y * 32;
  const int tx = threadIdx.x & 31, ty = threadIdx.x >> 5;  // ty 0..7
#pragma unroll
  for (int i = 0; i < 4; i++) {
    int k = k0 + ty + i * 8;
    t[ty + i * 8][tx] = src[(size_t)k * N + n0 + tx];
  }
  __syncthreads();
#pragma unroll
  for (int i = 0; i < 4; i++) {
    int n = n0 + ty + i * 8;
    dst[(size_t)n * 2048 + k0 + tx] = f2bf(t[tx][ty + i * 8]);
  }
}

// ---------------------------------------------------------------- GEMM  C = A[M][K] * Bt[N][K]^T
// 128x128 tile, BK=64, 4 waves (2x2), each wave 64x64 via 4x4 grid of 16x16x32 MFMAs.
template <int OUTF32>
__global__ __launch_bounds__(256) void k_gemm(const unsigned short* __restrict__ A,
                                              const unsigned short* __restrict__ Bt,
                                              void* __restrict__ Cp, int M, int N, int K) {
  __shared__ __align__(16) unsigned short As[128 * 64];
  __shared__ __align__(16) unsigned short Bs[128 * 64];
  const int nbx = N >> 7;
  const int nwg = gridDim.x;
  int wg = blockIdx.x;
  wg = (wg & 7) * (nwg >> 3) + (wg >> 3);  // XCD swizzle (nwg % 8 == 0 for our shapes)
  const int bx = wg % nbx, by = wg / nbx;
  const int m0 = by << 7, n0 = bx << 7;
  const int tid = threadIdx.x;
  const int lane = tid & 63, wid = tid >> 6;
  const int wm = (wid >> 1) * 64, wn = (wid & 1) * 64;
  const int l15 = lane & 15, kg = lane >> 4;
  const int srow = wid * 8 + (lane >> 3);  // staging row within each 32-row group
  const int scol = (lane & 7) * 8;         // staging col (elements)

  f32x4 acc[4][4] = {};

  for (int k0 = 0; k0 < K; k0 += 64) {
#pragma unroll
    for (int i = 0; i < 4; i++) {
      load16_lds(&A[(size_t)(m0 + i * 32 + srow) * K + k0 + scol], &As[(i * 32 + wid * 8) * 64]);
      load16_lds(&Bt[(size_t)(n0 + i * 32 + srow) * K + k0 + scol], &Bs[(i * 32 + wid * 8) * 64]);
    }
    __syncthreads();
#pragma unroll
    for (int kc = 0; kc < 2; kc++) {
      bf16x8 af[4], bfr[4];
#pragma unroll
      for (int mt = 0; mt < 4; mt++)
        af[mt] = *(const bf16x8*)&As[(wm + mt * 16 + l15) * 64 + kc * 32 + kg * 8];
#pragma unroll
      for (int nt = 0; nt < 4; nt++)
        bfr[nt] = *(const bf16x8*)&Bs[(wn + nt * 16 + l15) * 64 + kc * 32 + kg * 8];
#pragma unroll
      for (int mt = 0; mt < 4; mt++)
#pragma unroll
        for (int nt = 0; nt < 4; nt++)
          acc[mt][nt] = mfma16x16(af[mt], bfr[nt], acc[mt][nt]);
    }
    __syncthreads();
  }

  const int orow = m0 + wm + kg * 4;
#pragma unroll
  for (int mt = 0; mt < 4; mt++) {
#pragma unroll
    for (int nt = 0; nt < 4; nt++) {
      const int col = n0 + wn + nt * 16 + l15;
#pragma unroll
      for (int j = 0; j < 4; j++) {
        const size_t off = (size_t)(orow + mt * 16 + j) * N + col;
        if (OUTF32)
          ((float*)Cp)[off] = acc[mt][nt][j];
        else
          ((unsigned short*)Cp)[off] = f2bf(acc[mt][nt][j]);
      }
    }
  }
}

// ---------------------------------------------------------------- RoPE in-place on QKV (Q + K parts)
// per row (4096): 32 q-heads * 32 pairs + 8 k-heads * 32 pairs = 1280 pairs
__global__ __launch_bounds__(256) void k_rope(unsigned short* __restrict__ qkv,
                                              const float* __restrict__ ctab,
                                              const float* __restrict__ stab) {
  const int idx = blockIdx.x * 256 + threadIdx.x;  // 4096*1280 total, exact
  const int row = idx / 1280;
  const int r = idx - row * 1280;
  const int head = r >> 5, pair = r & 31;
  const int s = row & 1023;
  const int col = (head < 32) ? (head * 64 + pair * 2) : (2048 + (head - 32) * 64 + pair * 2);
  const float c = ctab[s * 32 + pair], sn = stab[s * 32 + pair];
  const size_t base = (size_t)row * 3072 + col;
  const float e = bf2f(qkv[base]), o = bf2f(qkv[base + 1]);
  qkv[base]     = f2bf(e * c - o * sn);
  qkv[base + 1] = f2bf(e * sn + o * c);
}

// ---------------------------------------------------------------- V -> VT  [ (b*8+kh)*64 + d ][ s ]
__global__ __launch_bounds__(256) void k_vt(const unsigned short* __restrict__ qkv,
                                            unsigned short* __restrict__ vt) {
  __shared__ unsigned short t[32][33];
  const int st0 = blockIdx.x * 32;
  const int d0 = blockIdx.y * 32;
  const int bkh = blockIdx.z;  // b*8+kh
  const int b = bkh >> 3, kh = bkh & 7;
  const int tx = threadIdx.x & 31, ty = threadIdx.x >> 5;
#pragma unroll
  for (int i = 0; i < 4; i++) {
    int s = st0 + ty + i * 8;
    t[ty + i * 8][tx] = qkv[(size_t)(b * 1024 + s) * 3072 + 2560 + kh * 64 + d0 + tx];
  }
  __syncthreads();
#pragma unroll
  for (int i = 0; i < 4; i++) {
    int d = d0 + ty + i * 8;
    vt[(size_t)(bkh * 64 + d) * 1024 + st0 + tx] = t[tx][ty + i * 8];
  }
}

// ---------------------------------------------------------------- flash attention (causal, GQA)
// grid: 2048 blocks = b(4) * h(32) * qtile(16).  4 waves, wave w owns q rows q0+w*16..+15.
// No __syncthreads: each wave uses its own P scratch. KV tile = 64.
__global__ __launch_bounds__(256) void k_attn(const unsigned short* __restrict__ qkv,
                                              const unsigned short* __restrict__ vt,
                                              unsigned short* __restrict__ ao) {
  __shared__ __align__(16) unsigned short P[4][16][80];  // per-wave, padded rows (160B)
  const int bid = blockIdx.x;
  const int qt = bid & 15, h = (bid >> 4) & 31, b = bid >> 9;
  const int q0 = qt << 6;
  const int wid = threadIdx.x >> 6, lane = threadIdx.x & 63;
  const int l15 = lane & 15, kg = lane >> 4;
  const int kh = h >> 2;
  const int qbase = b * 1024 + q0 + wid * 16;

  bf16x8 aq[2];
  {
    const size_t qoff = (size_t)(qbase + l15) * 3072 + h * 64 + kg * 8;
    aq[0] = *(const bf16x8*)&qkv[qoff];
    aq[1] = *(const bf16x8*)&qkv[qoff + 32];
  }

  f32x4 o[4] = {};
  float mrow[4] = {-__builtin_inff(), -__builtin_inff(), -__builtin_inff(), -__builtin_inff()};
  float lrow[4] = {0.f, 0.f, 0.f, 0.f};

  const int ntiles = ((q0 + wid * 16 + 15) >> 6) + 1;

  for (int t = 0; t < ntiles; t++) {
    const int kv0 = t << 6;
    f32x4 sc[4] = {};
#pragma unroll
    for (int ct = 0; ct < 4; ct++) {
      const size_t koff =
          (size_t)(b * 1024 + kv0 + ct * 16 + l15) * 3072 + 2048 + kh * 64 + kg * 8;
      bf16x8 bk0 = *(const bf16x8*)&qkv[koff];
      bf16x8 bk1 = *(const bf16x8*)&qkv[koff + 32];
      sc[ct] = mfma16x16(aq[0], bk0, sc[ct]);
      sc[ct] = mfma16x16(aq[1], bk1, sc[ct]);
    }
    // online softmax: C layout row = kg*4+reg, col = ct*16+l15
    float pv[4][4];
    float fac[4];
#pragma unroll
    for (int reg = 0; reg < 4; reg++) {
      const int rowg = q0 + wid * 16 + kg * 4 + reg;
      float rm = -__builtin_inff();
#pragma unroll
      for (int ct = 0; ct < 4; ct++) {
        float v = sc[ct][reg] * 0.125f;
        const int colg = kv0 + ct * 16 + l15;
        v = (colg > rowg) ? -__builtin_inff() : v;
        pv[ct][reg] = v;
        rm = fmaxf(rm, v);
      }
#pragma unroll
      for (int off = 1; off < 16; off <<= 1) rm = fmaxf(rm, __shfl_xor(rm, off));
      const float mnew = fmaxf(mrow[reg], rm);
      fac[reg] = __expf(mrow[reg] - mnew);  // -inf - finite -> 0
      float rs = 0.f;
#pragma unroll
      for (int ct = 0; ct < 4; ct++) {
        const float e = __expf(pv[ct][reg] - mnew);
        pv[ct][reg] = e;
        rs += e;
      }
#pragma unroll
      for (int off = 1; off < 16; off <<= 1) rs += __shfl_xor(rs, off);
      lrow[reg] = lrow[reg] * fac[reg] + rs;
      mrow[reg] = mnew;
    }
#pragma unroll
    for (int ct = 0; ct < 4; ct++) {
      o[ct][0] *= fac[0]; o[ct][1] *= fac[1]; o[ct][2] *= fac[2]; o[ct][3] *= fac[3];
    }
    // P tile to wave-private LDS (true coordinates), then read back as A-fragments
#pragma unroll
    for (int reg = 0; reg < 4; reg++)
#pragma unroll
      for (int ct = 0; ct < 4; ct++)
        P[wid][kg * 4 + reg][ct * 16 + l15] = f2bf(pv[ct][reg]);

    bf16x8 ap0 = *(const bf16x8*)&P[wid][l15][kg * 8];
    bf16x8 ap1 = *(const bf16x8*)&P[wid][l15][32 + kg * 8];
#pragma unroll
    for (int ct = 0; ct < 4; ct++) {
      const size_t voff = (size_t)((b * 8 + kh) * 64 + ct * 16 + l15) * 1024 + kv0 + kg * 8;
      bf16x8 bv0 = *(const bf16x8*)&vt[voff];
      bf16x8 bv1 = *(const bf16x8*)&vt[voff + 32];
      o[ct] = mfma16x16(ap0, bv0, o[ct]);
      o[ct] = mfma16x16(ap1, bv1, o[ct]);
    }
  }
  // epilogue: divide by l, write bf16
#pragma unroll
  for (int ct = 0; ct < 4; ct++) {
#pragma unroll
    for (int reg = 0; reg < 4; reg++) {
      const float val = o[ct][reg] / lrow[reg];
      ao[(size_t)(qbase + kg * 4 + reg) * 2048 + h * 64 + ct * 16 + l15] = f2bf(val);
    }
  }
}

// ---------------------------------------------------------------- launcher
extern "C" void kernel_launch(void* const* d_in, const int* in_sizes, int n_in,
                              void* d_out, int out_size, void* d_ws, size_t ws_size,
                              hipStream_t stream) {
  const float* x    = (const float*)d_in[0];
  const float* pcos = (const float*)d_in[1];
  const float* psin = (const float*)d_in[2];
  const float* wq   = (const float*)d_in[3];
  const float* wk   = (const float*)d_in[4];
  const float* wv   = (const float*)d_in[5];
  const float* wo   = (const float*)d_in[6];

  char* ws = (char*)d_ws;
  unsigned short* XB  = (unsigned short*)(ws);              // 4096x2048 bf16 (x, later attn-out)
  unsigned short* WT  = (unsigned short*)(ws + 16777216);   // 3072x2048 bf16 (wq|wk|wv)^T
  unsigned short* WOT = (unsigned short*)(ws + 29360128);   // 2048x2048 bf16 wo^T
  unsigned short* QKV = (unsigned short*)(ws + 37748736);   // 4096x3072 bf16
  unsigned short* VT  = (unsigned short*)(ws + 62914560);   // (4*8*64)x1024 bf16
  // total 64 MiB

  k_convert_x<<<8192, 256, 0, stream>>>(x, XB, 8388608);
  k_transpose_w<<<dim3(64, 64), 256, 0, stream>>>(wq, WT, 2048);
  k_transpose_w<<<dim3(16, 64), 256, 0, stream>>>(wk, WT + (size_t)2048 * 2048, 512);
  k_transpose_w<<<dim3(16, 64), 256, 0, stream>>>(wv, WT + (size_t)2560 * 2048, 512);
  k_transpose_w<<<dim3(64, 64), 256, 0, stream>>>(wo, WOT, 2048);

  k_gemm<0><<<768, 256, 0, stream>>>(XB, WT, QKV, 4096, 3072, 2048);
  k_rope<<<20480, 256, 0, stream>>>(QKV, pcos, psin);
  k_vt<<<dim3(32, 2, 32), 256, 0, stream>>>(QKV, VT);
  k_attn<<<2048, 256, 0, stream>>>(QKV, VT, XB);
  k_gemm<1><<<512, 256, 0, stream>>>(XB, WOT, d_out, 4096, 2048, 2048);
}

// Round 2
// 356.420 us; speedup vs baseline: 1.4553x; 1.4553x over previous
//
#include <hip/hip_runtime.h>
#include <hip/hip_bf16.h>

// Problem constants
// B=4, S=1024, D=2048, NH=32, NKV=8, HD=64, HALF=32, N_REP=4
// ROWS = B*S = 4096 ; QKV cols = 2048 + 512 + 512 = 3072

typedef __bf16 bf16x8 __attribute__((ext_vector_type(8)));
typedef float  f32x4  __attribute__((ext_vector_type(4)));

#define DEV static __device__ __forceinline__

DEV unsigned short f2bf(float f) {
  __hip_bfloat16 h = __float2bfloat16(f);
  unsigned short u;
  __builtin_memcpy(&u, &h, 2);
  return u;
}
DEV float bf2f(unsigned short u) {
  unsigned int ui = ((unsigned int)u) << 16;
  float f;
  __builtin_memcpy(&f, &ui, 4);
  return f;
}

typedef const unsigned int __attribute__((address_space(1)))* as1_u32cp;
typedef unsigned int __attribute__((address_space(3)))* as3_u32p;

// async global->LDS, 16B per lane. lds dest must be wave-uniform base; HW adds lane*16.
DEV void load16_lds(const unsigned short* g, unsigned short* l) {
  __builtin_amdgcn_global_load_lds((as1_u32cp)(unsigned long long)g,
                                   (as3_u32p)(unsigned int)(unsigned long long)l,
                                   16, 0, 0);
}

DEV f32x4 mfma16x16(bf16x8 a, bf16x8 b, f32x4 c) {
  return __builtin_amdgcn_mfma_f32_16x16x32_bf16(a, b, c, 0, 0, 0);
}

// ---------------------------------------------------------------- convert x -> bf16
__global__ __launch_bounds__(256) void k_convert_x(const float* __restrict__ x,
                                                   unsigned short* __restrict__ xb, int n) {
  int i = (blockIdx.x * 256 + threadIdx.x) * 4;
  if (i < n) {
    float4 v = *(const float4*)(x + i);
    ushort4 o;
    o.x = f2bf(v.x); o.y = f2bf(v.y); o.z = f2bf(v.z); o.w = f2bf(v.w);
    *(ushort4*)(xb + i) = o;
  }
}

// --------------------------------------------------- transpose fp32 [2048][N] -> bf16 [N][2048]
__global__ __launch_bounds__(256) void k_transpose_w(const float* __restrict__ src,
                                                     unsigned short* __restrict__ dst, int N) {
  __shared__ float t[32][33];
  const int n0 = blockIdx.x * 32, k0 = blockIdx.y * 32;
  const int tx = threadIdx.x & 31, ty = threadIdx.x >> 5;  // ty 0..7
#pragma unroll
  for (int i = 0; i < 4; i++) {
    int k = k0 + ty + i * 8;
    t[ty + i * 8][tx] = src[(size_t)k * N + n0 + tx];
  }
  __syncthreads();
#pragma unroll
  for (int i = 0; i < 4; i++) {
    int n = n0 + ty + i * 8;
    dst[(size_t)n * 2048 + k0 + tx] = f2bf(t[tx][ty + i * 8]);
  }
}

// ---------------------------------------------------------------- GEMM  C = A[M][K] * Bt[N][K]^T
// 128x128 tile, BK=64, 4 waves (2x2), each wave 64x64 via 4x4 grid of 16x16x32 MFMAs.
template <int OUTF32>
__global__ __launch_bounds__(256) void k_gemm(const unsigned short* __restrict__ A,
                                              const unsigned short* __restrict__ Bt,
                                              void* __restrict__ Cp, int M, int N, int K) {
  __shared__ __align__(16) unsigned short As[128 * 64];
  __shared__ __align__(16) unsigned short Bs[128 * 64];
  const int nbx = N >> 7;
  const int nwg = gridDim.x;
  int wg = blockIdx.x;
  wg = (wg & 7) * (nwg >> 3) + (wg >> 3);  // XCD swizzle (nwg % 8 == 0 for our shapes)
  const int bx = wg % nbx, by = wg / nbx;
  const int m0 = by << 7, n0 = bx << 7;
  const int tid = threadIdx.x;
  const int lane = tid & 63, wid = tid >> 6;
  const int wm = (wid >> 1) * 64, wn = (wid & 1) * 64;
  const int l15 = lane & 15, kg = lane >> 4;
  const int srow = wid * 8 + (lane >> 3);  // staging row within each 32-row group
  const int scol = (lane & 7) * 8;         // staging col (elements)

  f32x4 acc[4][4] = {};

  for (int k0 = 0; k0 < K; k0 += 64) {
#pragma unroll
    for (int i = 0; i < 4; i++) {
      load16_lds(&A[(size_t)(m0 + i * 32 + srow) * K + k0 + scol], &As[(i * 32 + wid * 8) * 64]);
      load16_lds(&Bt[(size_t)(n0 + i * 32 + srow) * K + k0 + scol], &Bs[(i * 32 + wid * 8) * 64]);
    }
    __syncthreads();
#pragma unroll
    for (int kc = 0; kc < 2; kc++) {
      bf16x8 af[4], bfr[4];
#pragma unroll
      for (int mt = 0; mt < 4; mt++)
        af[mt] = *(const bf16x8*)&As[(wm + mt * 16 + l15) * 64 + kc * 32 + kg * 8];
#pragma unroll
      for (int nt = 0; nt < 4; nt++)
        bfr[nt] = *(const bf16x8*)&Bs[(wn + nt * 16 + l15) * 64 + kc * 32 + kg * 8];
#pragma unroll
      for (int mt = 0; mt < 4; mt++)
#pragma unroll
        for (int nt = 0; nt < 4; nt++)
          acc[mt][nt] = mfma16x16(af[mt], bfr[nt], acc[mt][nt]);
    }
    __syncthreads();
  }

  const int orow = m0 + wm + kg * 4;
#pragma unroll
  for (int mt = 0; mt < 4; mt++) {
#pragma unroll
    for (int nt = 0; nt < 4; nt++) {
      const int col = n0 + wn + nt * 16 + l15;
#pragma unroll
      for (int j = 0; j < 4; j++) {
        const size_t off = (size_t)(orow + mt * 16 + j) * N + col;
        if (OUTF32)
          ((float*)Cp)[off] = acc[mt][nt][j];
        else
          ((unsigned short*)Cp)[off] = f2bf(acc[mt][nt][j]);
      }
    }
  }
}

// ---------------------------------------------------------------- RoPE in-place on QKV (Q + K parts)
__global__ __launch_bounds__(256) void k_rope(unsigned short* __restrict__ qkv,
                                              const float* __restrict__ ctab,
                                              const float* __restrict__ stab) {
  const int idx = blockIdx.x * 256 + threadIdx.x;  // 4096*1280 total, exact
  const int row = idx / 1280;
  const int r = idx - row * 1280;
  const int head = r >> 5, pair = r & 31;
  const int s = row & 1023;
  const int col = (head < 32) ? (head * 64 + pair * 2) : (2048 + (head - 32) * 64 + pair * 2);
  const float c = ctab[s * 32 + pair], sn = stab[s * 32 + pair];
  const size_t base = (size_t)row * 3072 + col;
  const float e = bf2f(qkv[base]), o = bf2f(qkv[base + 1]);
  qkv[base]     = f2bf(e * c - o * sn);
  qkv[base + 1] = f2bf(e * sn + o * c);
}

// ---------------------------------------------------------------- V -> VT  [ (b*8+kh)*64 + d ][ s ]
__global__ __launch_bounds__(256) void k_vt(const unsigned short* __restrict__ qkv,
                                            unsigned short* __restrict__ vt) {
  __shared__ unsigned short t[32][33];
  const int st0 = blockIdx.x * 32;
  const int d0 = blockIdx.y * 32;
  const int bkh = blockIdx.z;  // b*8+kh
  const int b = bkh >> 3, kh = bkh & 7;
  const int tx = threadIdx.x & 31, ty = threadIdx.x >> 5;
#pragma unroll
  for (int i = 0; i < 4; i++) {
    int s = st0 + ty + i * 8;
    t[ty + i * 8][tx] = qkv[(size_t)(b * 1024 + s) * 3072 + 2560 + kh * 64 + d0 + tx];
  }
  __syncthreads();
#pragma unroll
  for (int i = 0; i < 4; i++) {
    int d = d0 + ty + i * 8;
    vt[(size_t)(bkh * 64 + d) * 1024 + st0 + tx] = t[tx][ty + i * 8];
  }
}

// ---------------------------------------------------------------- flash attention (causal, GQA)
// grid: 2048 blocks; qt = 15 - (bid>>7) so heavy blocks dispatch first; hb = bid&127.
// 4 waves share K/V LDS staging (double-buffered, XOR-swizzled, global_load_lds),
// 2-phase pipeline: prefetch next tile before compute, one vmcnt(0)+s_barrier per tile.
__global__ __launch_bounds__(256) void k_attn(const unsigned short* __restrict__ qkv,
                                              const unsigned short* __restrict__ vt,
                                              unsigned short* __restrict__ ao) {
  __shared__ __align__(16) unsigned short Ks[2][64 * 64];
  __shared__ __align__(16) unsigned short Vs[2][64 * 64];
  __shared__ __align__(16) unsigned short P[4][16][72];  // per-wave P scratch

  const int bid = blockIdx.x;
  const int qt = 15 - (bid >> 7);
  const int hb = bid & 127;
  const int h = hb & 31, b = hb >> 5;
  const int q0 = qt << 6;
  const int wid = threadIdx.x >> 6, lane = threadIdx.x & 63;
  const int l15 = lane & 15, kg = lane >> 4;
  const int kh = h >> 2;
  const int qbase = b * 1024 + q0 + wid * 16;
  const int nt = qt + 1;

  // Q fragments held in registers for the whole block
  bf16x8 aq0, aq1;
  {
    const size_t qoff = (size_t)(qbase + l15) * 3072 + h * 64 + kg * 8;
    aq0 = *(const bf16x8*)&qkv[qoff];
    aq1 = *(const bf16x8*)&qkv[qoff + 32];
  }

  // staging geometry: lane l stages row (l>>3), 16B slot (l&7); source col is
  // inverse-XOR-swizzled so that the swizzled LDS read below sees linear data.
  const int l8 = lane >> 3;
  const int colel = ((lane & 7) ^ l8) * 8;  // element offset, pre-swizzled
  const size_t krowbase = (size_t)(b * 1024) * 3072 + 2048 + kh * 64 + colel;
  const size_t vrowbase = (size_t)((b * 8 + kh) * 64) * 1024 + colel;

  // prologue: stage tile 0
#pragma unroll
  for (int i = 0; i < 2; i++) {
    const int r = wid * 16 + i * 8 + l8;
    load16_lds(&qkv[krowbase + (size_t)r * 3072], &Ks[0][(wid * 16 + i * 8) * 64]);
    load16_lds(&vt[vrowbase + (size_t)r * 1024], &Vs[0][(wid * 16 + i * 8) * 64]);
  }
  asm volatile("s_waitcnt vmcnt(0)" ::: "memory");
  __builtin_amdgcn_s_barrier();

  f32x4 o[4] = {};
  float mrow[4] = {-__builtin_inff(), -__builtin_inff(), -__builtin_inff(), -__builtin_inff()};
  float lrow[4] = {0.f, 0.f, 0.f, 0.f};

  const int swz = (l15 & 7) * 8;  // read-side XOR swizzle (elements)

  for (int t = 0; t < nt; t++) {
    const int cur = t & 1;
    // prefetch next tile into the other buffer (stays in flight during compute)
    if (t + 1 < nt) {
      const size_t kv1 = (size_t)((t + 1) << 6);
#pragma unroll
      for (int i = 0; i < 2; i++) {
        const int r = wid * 16 + i * 8 + l8;
        load16_lds(&qkv[krowbase + (kv1 + r) * 3072], &Ks[cur ^ 1][(wid * 16 + i * 8) * 64]);
        load16_lds(&vt[vrowbase + (size_t)r * 1024 + kv1], &Vs[cur ^ 1][(wid * 16 + i * 8) * 64]);
      }
    }
    const int kv0 = t << 6;

    // QK^T from swizzled LDS
    f32x4 sc[4] = {};
#pragma unroll
    for (int ct = 0; ct < 4; ct++) {
      const unsigned short* kr = &Ks[cur][(ct * 16 + l15) * 64];
      bf16x8 bk0 = *(const bf16x8*)&kr[(kg * 8) ^ swz];
      bf16x8 bk1 = *(const bf16x8*)&kr[(kg * 8 + 32) ^ swz];
      sc[ct] = mfma16x16(aq0, bk0, sc[ct]);
      sc[ct] = mfma16x16(aq1, bk1, sc[ct]);
    }

    // online softmax: C layout row = kg*4+reg, col = ct*16+l15
    float pv[4][4];
    float fac[4];
#pragma unroll
    for (int reg = 0; reg < 4; reg++) {
      const int rowg = q0 + wid * 16 + kg * 4 + reg;
      float rm = -__builtin_inff();
#pragma unroll
      for (int ct = 0; ct < 4; ct++) {
        float v = sc[ct][reg] * 0.125f;
        const int colg = kv0 + ct * 16 + l15;
        v = (colg > rowg) ? -__builtin_inff() : v;
        pv[ct][reg] = v;
        rm = fmaxf(rm, v);
      }
#pragma unroll
      for (int off = 1; off < 16; off <<= 1) rm = fmaxf(rm, __shfl_xor(rm, off));
      const float mnew = fmaxf(mrow[reg], rm);
      fac[reg] = __expf(mrow[reg] - mnew);  // -inf - finite -> 0
      float rs = 0.f;
#pragma unroll
      for (int ct = 0; ct < 4; ct++) {
        const float e = __expf(pv[ct][reg] - mnew);
        pv[ct][reg] = e;
        rs += e;
      }
#pragma unroll
      for (int off = 1; off < 16; off <<= 1) rs += __shfl_xor(rs, off);
      lrow[reg] = lrow[reg] * fac[reg] + rs;
      mrow[reg] = mnew;
    }
#pragma unroll
    for (int ct = 0; ct < 4; ct++) {
      o[ct][0] *= fac[0]; o[ct][1] *= fac[1]; o[ct][2] *= fac[2]; o[ct][3] *= fac[3];
    }

    // P tile to wave-private LDS (true coordinates), then read back as A-fragments
#pragma unroll
    for (int reg = 0; reg < 4; reg++)
#pragma unroll
      for (int ct = 0; ct < 4; ct++)
        P[wid][kg * 4 + reg][ct * 16 + l15] = f2bf(pv[ct][reg]);

    bf16x8 ap0 = *(const bf16x8*)&P[wid][l15][kg * 8];
    bf16x8 ap1 = *(const bf16x8*)&P[wid][l15][32 + kg * 8];

    // PV from swizzled LDS (Vs rows are d, cols are s)
#pragma unroll
    for (int ct = 0; ct < 4; ct++) {
      const unsigned short* vr = &Vs[cur][(ct * 16 + l15) * 64];
      bf16x8 bv0 = *(const bf16x8*)&vr[(kg * 8) ^ swz];
      bf16x8 bv1 = *(const bf16x8*)&vr[(kg * 8 + 32) ^ swz];
      o[ct] = mfma16x16(ap0, bv0, o[ct]);
      o[ct] = mfma16x16(ap1, bv1, o[ct]);
    }

    // next tile's staging must be complete, and all waves done reading cur,
    // before cur^1 is consumed / cur is overwritten next iteration.
    asm volatile("s_waitcnt vmcnt(0)" ::: "memory");
    __builtin_amdgcn_s_barrier();
  }

  // epilogue: divide by l, write bf16
#pragma unroll
  for (int ct = 0; ct < 4; ct++) {
#pragma unroll
    for (int reg = 0; reg < 4; reg++) {
      const float val = o[ct][reg] / lrow[reg];
      ao[(size_t)(qbase + kg * 4 + reg) * 2048 + h * 64 + ct * 16 + l15] = f2bf(val);
    }
  }
}

// ---------------------------------------------------------------- launcher
extern "C" void kernel_launch(void* const* d_in, const int* in_sizes, int n_in,
                              void* d_out, int out_size, void* d_ws, size_t ws_size,
                              hipStream_t stream) {
  const float* x    = (const float*)d_in[0];
  const float* pcos = (const float*)d_in[1];
  const float* psin = (const float*)d_in[2];
  const float* wq   = (const float*)d_in[3];
  const float* wk   = (const float*)d_in[4];
  const float* wv   = (const float*)d_in[5];
  const float* wo   = (const float*)d_in[6];

  char* ws = (char*)d_ws;
  unsigned short* XB  = (unsigned short*)(ws);              // 4096x2048 bf16 (x, later attn-out)
  unsigned short* WT  = (unsigned short*)(ws + 16777216);   // 3072x2048 bf16 (wq|wk|wv)^T
  unsigned short* WOT = (unsigned short*)(ws + 29360128);   // 2048x2048 bf16 wo^T
  unsigned short* QKV = (unsigned short*)(ws + 37748736);   // 4096x3072 bf16
  unsigned short* VT  = (unsigned short*)(ws + 62914560);   // (4*8*64)x1024 bf16
  // total 64 MiB

  k_convert_x<<<8192, 256, 0, stream>>>(x, XB, 8388608);
  k_transpose_w<<<dim3(64, 64), 256, 0, stream>>>(wq, WT, 2048);
  k_transpose_w<<<dim3(16, 64), 256, 0, stream>>>(wk, WT + (size_t)2048 * 2048, 512);
  k_transpose_w<<<dim3(16, 64), 256, 0, stream>>>(wv, WT + (size_t)2560 * 2048, 512);
  k_transpose_w<<<dim3(64, 64), 256, 0, stream>>>(wo, WOT, 2048);

  k_gemm<0><<<768, 256, 0, stream>>>(XB, WT, QKV, 4096, 3072, 2048);
  k_rope<<<20480, 256, 0, stream>>>(QKV, pcos, psin);
  k_vt<<<dim3(32, 2, 32), 256, 0, stream>>>(QKV, VT);
  k_attn<<<2048, 256, 0, stream>>>(QKV, VT, XB);
  k_gemm<1><<<512, 256, 0, stream>>>(XB, WOT, d_out, 4096, 2048, 2048);
}

// Round 3
// 336.960 us; speedup vs baseline: 1.5393x; 1.0578x over previous
//
#include <hip/hip_runtime.h>
#include <hip/hip_bf16.h>

// Problem constants
// B=4, S=1024, D=2048, NH=32, NKV=8, HD=64, HALF=32, N_REP=4
// ROWS = B*S = 4096 ; QKV cols = 2048 + 512 + 512 = 3072

typedef __bf16 bf16x8 __attribute__((ext_vector_type(8)));
typedef float  f32x4  __attribute__((ext_vector_type(4)));

#define DEV static __device__ __forceinline__

DEV unsigned short f2bf(float f) {
  __hip_bfloat16 h = __float2bfloat16(f);
  unsigned short u;
  __builtin_memcpy(&u, &h, 2);
  return u;
}
DEV float bf2f(unsigned short u) {
  unsigned int ui = ((unsigned int)u) << 16;
  float f;
  __builtin_memcpy(&f, &ui, 4);
  return f;
}

typedef const unsigned int __attribute__((address_space(1)))* as1_u32cp;
typedef unsigned int __attribute__((address_space(3)))* as3_u32p;

// async global->LDS, 16B per lane. lds dest must be wave-uniform base; HW adds lane*16.
DEV void load16_lds(const unsigned short* g, unsigned short* l) {
  __builtin_amdgcn_global_load_lds((as1_u32cp)(unsigned long long)g,
                                   (as3_u32p)(unsigned int)(unsigned long long)l,
                                   16, 0, 0);
}

DEV f32x4 mfma16x16(bf16x8 a, bf16x8 b, f32x4 c) {
  return __builtin_amdgcn_mfma_f32_16x16x32_bf16(a, b, c, 0, 0, 0);
}

// ---------------------------------------------------------------- convert x -> bf16
__global__ __launch_bounds__(256) void k_convert_x(const float* __restrict__ x,
                                                   unsigned short* __restrict__ xb, int n) {
  int i = (blockIdx.x * 256 + threadIdx.x) * 4;
  if (i < n) {
    float4 v = *(const float4*)(x + i);
    ushort4 o;
    o.x = f2bf(v.x); o.y = f2bf(v.y); o.z = f2bf(v.z); o.w = f2bf(v.w);
    *(ushort4*)(xb + i) = o;
  }
}

// --------------------------------------------------- transpose fp32 [2048][N] -> bf16 [N][2048]
__global__ __launch_bounds__(256) void k_transpose_w(const float* __restrict__ src,
                                                     unsigned short* __restrict__ dst, int N) {
  __shared__ float t[32][33];
  const int n0 = blockIdx.x * 32, k0 = blockIdx.y * 32;
  const int tx = threadIdx.x & 31, ty = threadIdx.x >> 5;  // ty 0..7
#pragma unroll
  for (int i = 0; i < 4; i++) {
    int k = k0 + ty + i * 8;
    t[ty + i * 8][tx] = src[(size_t)k * N + n0 + tx];
  }
  __syncthreads();
#pragma unroll
  for (int i = 0; i < 4; i++) {
    int n = n0 + ty + i * 8;
    dst[(size_t)n * 2048 + k0 + tx] = f2bf(t[tx][ty + i * 8]);
  }
}

// ---------------------------------------------------------------- GEMM  C = A[M][K] * Bt[N][K]^T
// 256x256 tile, BK=64, 8 waves (2M x 4N), 8-phase-style schedule:
// T2 LDS xor-swizzle + T3 quadrant phases + T4 counted vmcnt + T5 setprio.
// LDS: 2 dbuf x (A 256x64 + B 256x64) bf16 = 128 KiB. 1 block/CU.
// Swizzle: LDS(row, slot16B) holds global col-slot (slot ^ (row&7)); read with same XOR.

DEV bf16x8 ldfrag(const unsigned short* base, int row, int colslot) {
  return *(const bf16x8*)&base[row * 64 + (((colslot) ^ (row & 7)) << 3)];
}

template <int OUTF32>
__global__ __launch_bounds__(512) void k_gemm8(const unsigned short* __restrict__ A,
                                               const unsigned short* __restrict__ Bt,
                                               void* __restrict__ Cp, int M, int N, int K) {
  __shared__ __align__(16) unsigned short As[2][16384];
  __shared__ __align__(16) unsigned short Bs[2][16384];
  const int nbx = N >> 8;
  const int nwg = gridDim.x;
  int wg = blockIdx.x;
  wg = (wg & 7) * (nwg >> 3) + (wg >> 3);  // XCD swizzle (nwg % 8 == 0 here)
  const int bx = wg % nbx, by = wg / nbx;
  const int m0 = by << 8, n0 = bx << 8;
  const int tid = threadIdx.x;
  const int lane = tid & 63, wid = tid >> 6;
  const int wm = wid >> 2, wn = wid & 3;       // wave 128x64 output at (wm*128, wn*64)
  const int l15 = lane & 15, kg = lane >> 4;
  const int NT = K >> 6;

  // staging geometry: thread covers (row_local = tid>>3, 16B slot = tid&7) of each
  // 64-row group; global col pre-swizzled so linear LDS + XOR read line up.
  const int rl = tid >> 3;
  const int gcol = (((tid & 7) ^ (rl & 7)) << 3);
  const unsigned short* Ag = &A[(size_t)(m0 + rl) * K + gcol];
  const unsigned short* Bg = &Bt[(size_t)(n0 + rl) * K + gcol];
  const int ldsb = wid * 8 * 64;  // wave's chunk base (elements) within each 64-row group

#define STAGE_TILE(buf, kt)                                                        \
  {                                                                                \
    const int _k0 = (kt) << 6;                                                     \
    _Pragma("unroll") for (int i = 0; i < 4; i++)                                  \
        load16_lds(&Ag[(size_t)(i * 64) * K + _k0], &As[buf][i * 64 * 64 + ldsb]); \
    _Pragma("unroll") for (int i = 0; i < 4; i++)                                  \
        load16_lds(&Bg[(size_t)(i * 64) * K + _k0], &Bs[buf][i * 64 * 64 + ldsb]); \
  }

  f32x4 acc[8][4] = {};

  // prologue: stage tiles 0 and 1; wait tile 0 (tile 1's 8 loads stay in flight)
  STAGE_TILE(0, 0)
  STAGE_TILE(1, 1)
  asm volatile("s_waitcnt vmcnt(8)" ::: "memory");
  __builtin_amdgcn_s_barrier();

  for (int t = 0; t < NT; t++) {
    const unsigned short* at = As[t & 1];
    const unsigned short* bt = Bs[t & 1];
    bf16x8 af[4][2], bfr[2][2];

    // ---- phase 1: quadrant (m-half 0, n-half 0) : 12 ds_read + 16 MFMA
#pragma unroll
    for (int fm = 0; fm < 4; fm++)
#pragma unroll
      for (int kc = 0; kc < 2; kc++)
        af[fm][kc] = ldfrag(at, wm * 128 + fm * 16 + l15, kc * 4 + kg);
#pragma unroll
    for (int fn = 0; fn < 2; fn++)
#pragma unroll
      for (int kc = 0; kc < 2; kc++)
        bfr[fn][kc] = ldfrag(bt, wn * 64 + fn * 16 + l15, kc * 4 + kg);
    __builtin_amdgcn_s_barrier();
    __builtin_amdgcn_s_setprio(1);
#pragma unroll
    for (int fm = 0; fm < 4; fm++)
#pragma unroll
      for (int fn = 0; fn < 2; fn++)
#pragma unroll
        for (int kc = 0; kc < 2; kc++)
          acc[fm][fn] = mfma16x16(af[fm][kc], bfr[fn][kc], acc[fm][fn]);
    __builtin_amdgcn_s_setprio(0);
    __builtin_amdgcn_s_barrier();

    // ---- phase 2: (m0, n-half 1) : 4 ds_read + 16 MFMA (reuse af)
#pragma unroll
    for (int fn = 0; fn < 2; fn++)
#pragma unroll
      for (int kc = 0; kc < 2; kc++)
        bfr[fn][kc] = ldfrag(bt, wn * 64 + (2 + fn) * 16 + l15, kc * 4 + kg);
    __builtin_amdgcn_s_barrier();
    __builtin_amdgcn_s_setprio(1);
#pragma unroll
    for (int fm = 0; fm < 4; fm++)
#pragma unroll
      for (int fn = 0; fn < 2; fn++)
#pragma unroll
        for (int kc = 0; kc < 2; kc++)
          acc[fm][2 + fn] = mfma16x16(af[fm][kc], bfr[fn][kc], acc[fm][2 + fn]);
    __builtin_amdgcn_s_setprio(0);
    __builtin_amdgcn_s_barrier();

    // ---- phase 3: (m-half 1, n1) : 8 ds_read + 16 MFMA (reuse bfr)
#pragma unroll
    for (int fm = 0; fm < 4; fm++)
#pragma unroll
      for (int kc = 0; kc < 2; kc++)
        af[fm][kc] = ldfrag(at, wm * 128 + (4 + fm) * 16 + l15, kc * 4 + kg);
    __builtin_amdgcn_s_barrier();
    __builtin_amdgcn_s_setprio(1);
#pragma unroll
    for (int fm = 0; fm < 4; fm++)
#pragma unroll
      for (int fn = 0; fn < 2; fn++)
#pragma unroll
        for (int kc = 0; kc < 2; kc++)
          acc[4 + fm][2 + fn] = mfma16x16(af[fm][kc], bfr[fn][kc], acc[4 + fm][2 + fn]);
    __builtin_amdgcn_s_setprio(0);
    __builtin_amdgcn_s_barrier();

    // ---- phase 4: (m1, n-half 0) : 4 ds_read + 16 MFMA (reuse af)
#pragma unroll
    for (int fn = 0; fn < 2; fn++)
#pragma unroll
      for (int kc = 0; kc < 2; kc++)
        bfr[fn][kc] = ldfrag(bt, wn * 64 + fn * 16 + l15, kc * 4 + kg);
    __builtin_amdgcn_s_barrier();
    __builtin_amdgcn_s_setprio(1);
#pragma unroll
    for (int fm = 0; fm < 4; fm++)
#pragma unroll
      for (int fn = 0; fn < 2; fn++)
#pragma unroll
        for (int kc = 0; kc < 2; kc++)
          acc[4 + fm][fn] = mfma16x16(af[fm][kc], bfr[fn][kc], acc[4 + fm][fn]);
    __builtin_amdgcn_s_setprio(0);
    __builtin_amdgcn_s_barrier();  // all waves done reading buf (t&1)

    // ---- tile boundary: stage t+2 into the just-freed buffer, counted vmcnt
    if (t + 2 < NT) {
      STAGE_TILE(t & 1, t + 2)
      asm volatile("s_waitcnt vmcnt(8)" ::: "memory");  // t+1's 8 loads landed; t+2's in flight
    } else {
      asm volatile("s_waitcnt vmcnt(0)" ::: "memory");
    }
    __builtin_amdgcn_s_barrier();
  }
#undef STAGE_TILE

  // epilogue: C layout col=l15, row=kg*4+j per 16x16 frag
  const int orow = m0 + wm * 128 + kg * 4;
#pragma unroll
  for (int fm = 0; fm < 8; fm++) {
#pragma unroll
    for (int fn = 0; fn < 4; fn++) {
      const int col = n0 + wn * 64 + fn * 16 + l15;
#pragma unroll
      for (int j = 0; j < 4; j++) {
        const size_t off = (size_t)(orow + fm * 16 + j) * N + col;
        if (OUTF32)
          ((float*)Cp)[off] = acc[fm][fn][j];
        else
          ((unsigned short*)Cp)[off] = f2bf(acc[fm][fn][j]);
      }
    }
  }
}

// ---------------------------------------------------------------- RoPE in-place on QKV (Q + K parts)
__global__ __launch_bounds__(256) void k_rope(unsigned short* __restrict__ qkv,
                                              const float* __restrict__ ctab,
                                              const float* __restrict__ stab) {
  const int idx = blockIdx.x * 256 + threadIdx.x;  // 4096*1280 total, exact
  const int row = idx / 1280;
  const int r = idx - row * 1280;
  const int head = r >> 5, pair = r & 31;
  const int s = row & 1023;
  const int col = (head < 32) ? (head * 64 + pair * 2) : (2048 + (head - 32) * 64 + pair * 2);
  const float c = ctab[s * 32 + pair], sn = stab[s * 32 + pair];
  const size_t base = (size_t)row * 3072 + col;
  const float e = bf2f(qkv[base]), o = bf2f(qkv[base + 1]);
  qkv[base]     = f2bf(e * c - o * sn);
  qkv[base + 1] = f2bf(e * sn + o * c);
}

// ---------------------------------------------------------------- V -> VT  [ (b*8+kh)*64 + d ][ s ]
__global__ __launch_bounds__(256) void k_vt(const unsigned short* __restrict__ qkv,
                                            unsigned short* __restrict__ vt) {
  __shared__ unsigned short t[32][33];
  const int st0 = blockIdx.x * 32;
  const int d0 = blockIdx.y * 32;
  const int bkh = blockIdx.z;  // b*8+kh
  const int b = bkh >> 3, kh = bkh & 7;
  const int tx = threadIdx.x & 31, ty = threadIdx.x >> 5;
#pragma unroll
  for (int i = 0; i < 4; i++) {
    int s = st0 + ty + i * 8;
    t[ty + i * 8][tx] = qkv[(size_t)(b * 1024 + s) * 3072 + 2560 + kh * 64 + d0 + tx];
  }
  __syncthreads();
#pragma unroll
  for (int i = 0; i < 4; i++) {
    int d = d0 + ty + i * 8;
    vt[(size_t)(bkh * 64 + d) * 1024 + st0 + tx] = t[tx][ty + i * 8];
  }
}

// ---------------------------------------------------------------- flash attention (causal, GQA)
// grid: 2048 blocks; qt = 15 - (bid>>7) so heavy blocks dispatch first; hb = bid&127.
// 4 waves share K/V LDS staging (double-buffered, XOR-swizzled, global_load_lds),
// 2-phase pipeline: prefetch next tile before compute, one vmcnt(0)+s_barrier per tile.
__global__ __launch_bounds__(256) void k_attn(const unsigned short* __restrict__ qkv,
                                              const unsigned short* __restrict__ vt,
                                              unsigned short* __restrict__ ao) {
  __shared__ __align__(16) unsigned short Ks[2][64 * 64];
  __shared__ __align__(16) unsigned short Vs[2][64 * 64];
  __shared__ __align__(16) unsigned short P[4][16][72];  // per-wave P scratch

  const int bid = blockIdx.x;
  const int qt = 15 - (bid >> 7);
  const int hb = bid & 127;
  const int h = hb & 31, b = hb >> 5;
  const int q0 = qt << 6;
  const int wid = threadIdx.x >> 6, lane = threadIdx.x & 63;
  const int l15 = lane & 15, kg = lane >> 4;
  const int kh = h >> 2;
  const int qbase = b * 1024 + q0 + wid * 16;
  const int nt = qt + 1;

  // Q fragments held in registers for the whole block
  bf16x8 aq0, aq1;
  {
    const size_t qoff = (size_t)(qbase + l15) * 3072 + h * 64 + kg * 8;
    aq0 = *(const bf16x8*)&qkv[qoff];
    aq1 = *(const bf16x8*)&qkv[qoff + 32];
  }

  // staging geometry: lane l stages row (l>>3), 16B slot (l&7); source col is
  // inverse-XOR-swizzled so that the swizzled LDS read below sees linear data.
  const int l8 = lane >> 3;
  const int colel = ((lane & 7) ^ l8) * 8;  // element offset, pre-swizzled
  const size_t krowbase = (size_t)(b * 1024) * 3072 + 2048 + kh * 64 + colel;
  const size_t vrowbase = (size_t)((b * 8 + kh) * 64) * 1024 + colel;

  // prologue: stage tile 0
#pragma unroll
  for (int i = 0; i < 2; i++) {
    const int r = wid * 16 + i * 8 + l8;
    load16_lds(&qkv[krowbase + (size_t)r * 3072], &Ks[0][(wid * 16 + i * 8) * 64]);
    load16_lds(&vt[vrowbase + (size_t)r * 1024], &Vs[0][(wid * 16 + i * 8) * 64]);
  }
  asm volatile("s_waitcnt vmcnt(0)" ::: "memory");
  __builtin_amdgcn_s_barrier();

  f32x4 o[4] = {};
  float mrow[4] = {-__builtin_inff(), -__builtin_inff(), -__builtin_inff(), -__builtin_inff()};
  float lrow[4] = {0.f, 0.f, 0.f, 0.f};

  const int swz = (l15 & 7) * 8;  // read-side XOR swizzle (elements)

  for (int t = 0; t < nt; t++) {
    const int cur = t & 1;
    // prefetch next tile into the other buffer (stays in flight during compute)
    if (t + 1 < nt) {
      const size_t kv1 = (size_t)((t + 1) << 6);
#pragma unroll
      for (int i = 0; i < 2; i++) {
        const int r = wid * 16 + i * 8 + l8;
        load16_lds(&qkv[krowbase + (kv1 + r) * 3072], &Ks[cur ^ 1][(wid * 16 + i * 8) * 64]);
        load16_lds(&vt[vrowbase + (size_t)r * 1024 + kv1], &Vs[cur ^ 1][(wid * 16 + i * 8) * 64]);
      }
    }
    const int kv0 = t << 6;

    // QK^T from swizzled LDS
    f32x4 sc[4] = {};
#pragma unroll
    for (int ct = 0; ct < 4; ct++) {
      const unsigned short* kr = &Ks[cur][(ct * 16 + l15) * 64];
      bf16x8 bk0 = *(const bf16x8*)&kr[(kg * 8) ^ swz];
      bf16x8 bk1 = *(const bf16x8*)&kr[(kg * 8 + 32) ^ swz];
      sc[ct] = mfma16x16(aq0, bk0, sc[ct]);
      sc[ct] = mfma16x16(aq1, bk1, sc[ct]);
    }

    // online softmax: C layout row = kg*4+reg, col = ct*16+l15
    float pv[4][4];
    float fac[4];
#pragma unroll
    for (int reg = 0; reg < 4; reg++) {
      const int rowg = q0 + wid * 16 + kg * 4 + reg;
      float rm = -__builtin_inff();
#pragma unroll
      for (int ct = 0; ct < 4; ct++) {
        float v = sc[ct][reg] * 0.125f;
        const int colg = kv0 + ct * 16 + l15;
        v = (colg > rowg) ? -__builtin_inff() : v;
        pv[ct][reg] = v;
        rm = fmaxf(rm, v);
      }
#pragma unroll
      for (int off = 1; off < 16; off <<= 1) rm = fmaxf(rm, __shfl_xor(rm, off));
      const float mnew = fmaxf(mrow[reg], rm);
      fac[reg] = __expf(mrow[reg] - mnew);  // -inf - finite -> 0
      float rs = 0.f;
#pragma unroll
      for (int ct = 0; ct < 4; ct++) {
        const float e = __expf(pv[ct][reg] - mnew);
        pv[ct][reg] = e;
        rs += e;
      }
#pragma unroll
      for (int off = 1; off < 16; off <<= 1) rs += __shfl_xor(rs, off);
      lrow[reg] = lrow[reg] * fac[reg] + rs;
      mrow[reg] = mnew;
    }
#pragma unroll
    for (int ct = 0; ct < 4; ct++) {
      o[ct][0] *= fac[0]; o[ct][1] *= fac[1]; o[ct][2] *= fac[2]; o[ct][3] *= fac[3];
    }

    // P tile to wave-private LDS (true coordinates), then read back as A-fragments
#pragma unroll
    for (int reg = 0; reg < 4; reg++)
#pragma unroll
      for (int ct = 0; ct < 4; ct++)
        P[wid][kg * 4 + reg][ct * 16 + l15] = f2bf(pv[ct][reg]);

    bf16x8 ap0 = *(const bf16x8*)&P[wid][l15][kg * 8];
    bf16x8 ap1 = *(const bf16x8*)&P[wid][l15][32 + kg * 8];

    // PV from swizzled LDS (Vs rows are d, cols are s)
#pragma unroll
    for (int ct = 0; ct < 4; ct++) {
      const unsigned short* vr = &Vs[cur][(ct * 16 + l15) * 64];
      bf16x8 bv0 = *(const bf16x8*)&vr[(kg * 8) ^ swz];
      bf16x8 bv1 = *(const bf16x8*)&vr[(kg * 8 + 32) ^ swz];
      o[ct] = mfma16x16(ap0, bv0, o[ct]);
      o[ct] = mfma16x16(ap1, bv1, o[ct]);
    }

    // next tile's staging must be complete, and all waves done reading cur,
    // before cur^1 is consumed / cur is overwritten next iteration.
    asm volatile("s_waitcnt vmcnt(0)" ::: "memory");
    __builtin_amdgcn_s_barrier();
  }

  // epilogue: divide by l, write bf16
#pragma unroll
  for (int ct = 0; ct < 4; ct++) {
#pragma unroll
    for (int reg = 0; reg < 4; reg++) {
      const float val = o[ct][reg] / lrow[reg];
      ao[(size_t)(qbase + kg * 4 + reg) * 2048 + h * 64 + ct * 16 + l15] = f2bf(val);
    }
  }
}

// ---------------------------------------------------------------- launcher
extern "C" void kernel_launch(void* const* d_in, const int* in_sizes, int n_in,
                              void* d_out, int out_size, void* d_ws, size_t ws_size,
                              hipStream_t stream) {
  const float* x    = (const float*)d_in[0];
  const float* pcos = (const float*)d_in[1];
  const float* psin = (const float*)d_in[2];
  const float* wq   = (const float*)d_in[3];
  const float* wk   = (const float*)d_in[4];
  const float* wv   = (const float*)d_in[5];
  const float* wo   = (const float*)d_in[6];

  char* ws = (char*)d_ws;
  unsigned short* XB  = (unsigned short*)(ws);              // 4096x2048 bf16 (x, later attn-out)
  unsigned short* WT  = (unsigned short*)(ws + 16777216);   // 3072x2048 bf16 (wq|wk|wv)^T
  unsigned short* WOT = (unsigned short*)(ws + 29360128);   // 2048x2048 bf16 wo^T
  unsigned short* QKV = (unsigned short*)(ws + 37748736);   // 4096x3072 bf16
  unsigned short* VT  = (unsigned short*)(ws + 62914560);   // (4*8*64)x1024 bf16
  // total 64 MiB

  k_convert_x<<<8192, 256, 0, stream>>>(x, XB, 8388608);
  k_transpose_w<<<dim3(64, 64), 256, 0, stream>>>(wq, WT, 2048);
  k_transpose_w<<<dim3(16, 64), 256, 0, stream>>>(wk, WT + (size_t)2048 * 2048, 512);
  k_transpose_w<<<dim3(16, 64), 256, 0, stream>>>(wv, WT + (size_t)2560 * 2048, 512);
  k_transpose_w<<<dim3(64, 64), 256, 0, stream>>>(wo, WOT, 2048);

  k_gemm8<0><<<192, 512, 0, stream>>>(XB, WT, QKV, 4096, 3072, 2048);
  k_rope<<<20480, 256, 0, stream>>>(QKV, pcos, psin);
  k_vt<<<dim3(32, 2, 32), 256, 0, stream>>>(QKV, VT);
  k_attn<<<2048, 256, 0, stream>>>(QKV, VT, XB);
  k_gemm8<1><<<128, 512, 0, stream>>>(XB, WOT, d_out, 4096, 2048, 2048);
}

// Round 4
// 302.309 us; speedup vs baseline: 1.7158x; 1.1146x over previous
//
#include <hip/hip_runtime.h>
#include <hip/hip_bf16.h>

// Problem constants
// B=4, S=1024, D=2048, NH=32, NKV=8, HD=64, HALF=32, N_REP=4
// ROWS = B*S = 4096 ; QKV cols = 2048 + 512 + 512 = 3072

typedef __bf16 bf16x8 __attribute__((ext_vector_type(8)));
typedef float  f32x4  __attribute__((ext_vector_type(4)));

#define DEV static __device__ __forceinline__

DEV unsigned short f2bf(float f) {
  __hip_bfloat16 h = __float2bfloat16(f);
  unsigned short u;
  __builtin_memcpy(&u, &h, 2);
  return u;
}
DEV float bf2f(unsigned short u) {
  unsigned int ui = ((unsigned int)u) << 16;
  float f;
  __builtin_memcpy(&f, &ui, 4);
  return f;
}

typedef const unsigned int __attribute__((address_space(1)))* as1_u32cp;
typedef unsigned int __attribute__((address_space(3)))* as3_u32p;

// async global->LDS, 16B per lane. lds dest must be wave-uniform base; HW adds lane*16.
DEV void load16_lds(const unsigned short* g, unsigned short* l) {
  __builtin_amdgcn_global_load_lds((as1_u32cp)(unsigned long long)g,
                                   (as3_u32p)(unsigned int)(unsigned long long)l,
                                   16, 0, 0);
}

DEV f32x4 mfma16x16(bf16x8 a, bf16x8 b, f32x4 c) {
  return __builtin_amdgcn_mfma_f32_16x16x32_bf16(a, b, c, 0, 0, 0);
}

// ---------------------------------------------------------------- convert x -> bf16
__global__ __launch_bounds__(256) void k_convert_x(const float* __restrict__ x,
                                                   unsigned short* __restrict__ xb, int n) {
  int i = (blockIdx.x * 256 + threadIdx.x) * 4;
  if (i < n) {
    float4 v = *(const float4*)(x + i);
    ushort4 o;
    o.x = f2bf(v.x); o.y = f2bf(v.y); o.z = f2bf(v.z); o.w = f2bf(v.w);
    *(ushort4*)(xb + i) = o;
  }
}

// --------------------------------------------------- transpose fp32 [2048][N] -> bf16 [N][2048]
__global__ __launch_bounds__(256) void k_transpose_w(const float* __restrict__ src,
                                                     unsigned short* __restrict__ dst, int N) {
  __shared__ float t[32][33];
  const int n0 = blockIdx.x * 32, k0 = blockIdx.y * 32;
  const int tx = threadIdx.x & 31, ty = threadIdx.x >> 5;  // ty 0..7
#pragma unroll
  for (int i = 0; i < 4; i++) {
    int k = k0 + ty + i * 8;
    t[ty + i * 8][tx] = src[(size_t)k * N + n0 + tx];
  }
  __syncthreads();
#pragma unroll
  for (int i = 0; i < 4; i++) {
    int n = n0 + ty + i * 8;
    dst[(size_t)n * 2048 + k0 + tx] = f2bf(t[tx][ty + i * 8]);
  }
}

// ---------------------------------------------------------------- GEMM  C = A[M][K] * Bt[N][K]^T
// 256xBN tile, K processed in 32-col halves, 4 LDS slots per operand (depth-3 prefetch).
// 8 waves (WM x WN). Per tile (=2 halves): 4 phases, each {ds_read frags; issue 2 stage
// loads; barrier; setprio MFMA}; counted vmcnt at pair ends only (T3+T4), T2 swizzle
// slot^=(row>>1)&3 with inverse-swizzled global source, T5 setprio.
template <int OUTF32, int BN, int WM, int WN>
__global__ __launch_bounds__(512) void k_gemm8(const unsigned short* __restrict__ A,
                                               const unsigned short* __restrict__ Bt,
                                               void* __restrict__ Cp, int M, int N, int K) {
  constexpr int BM = 256;
  constexpr int FM = BM / WM / 16;  // m-frags per wave
  constexpr int FN = BN / WN / 16;  // n-frags per wave
  constexpr int LA = BM * 4 / 512;  // A stage loads per thread per half (2)
  constexpr int LB = BN * 4 / 512;  // B stage loads per thread per half (2 or 1)
  constexpr int LH = LA + LB;
  __shared__ __align__(16) unsigned short As[4][BM * 32];
  __shared__ __align__(16) unsigned short Bs[4][BN * 32];

  const int nbx = N / BN;
  const int nwg = gridDim.x;
  int wg = blockIdx.x;
  wg = (wg & 7) * (nwg >> 3) + (wg >> 3);  // XCD swizzle (nwg % 8 == 0 here)
  const int bx = wg % nbx, by = wg / nbx;
  const int m0 = by << 8, n0 = bx * BN;
  const int tid = threadIdx.x;
  const int lane = tid & 63, wid = tid >> 6;
  const int wm = wid / WN, wn = wid % WN;
  const int l15 = lane & 15, kg = lane >> 4;
  const int H = K >> 5;   // 32-col halves
  const int NT = K >> 6;  // 64-col tiles

  // staging: slot-unit u = i*512 + tid; row = u>>2, slot16B = u&3; global col
  // inverse-swizzled so linear LDS + XOR read line up.
  auto stageA = [&](int h, int i) {
    const int u = i * 512 + tid;
    const int row = u >> 2, sl = u & 3;
    const int gc = ((sl ^ ((row >> 1) & 3)) << 3);
    load16_lds(&A[(size_t)(m0 + row) * K + (h << 5) + gc],
               &As[h & 3][(i * 512 + (tid & ~63)) * 8]);
  };
  auto stageB = [&](int h, int i) {
    const int u = i * 512 + tid;
    const int row = u >> 2, sl = u & 3;
    const int gc = ((sl ^ ((row >> 1) & 3)) << 3);
    load16_lds(&Bt[(size_t)(n0 + row) * K + (h << 5) + gc],
               &Bs[h & 3][(i * 512 + (tid & ~63)) * 8]);
  };
  auto lda = [&](int s, int r) {
    return *(const bf16x8*)&As[s][r * 32 + ((kg ^ ((r >> 1) & 3)) << 3)];
  };
  auto ldb = [&](int s, int r) {
    return *(const bf16x8*)&Bs[s][r * 32 + ((kg ^ ((r >> 1) & 3)) << 3)];
  };

#define VMCNT_C2(c)                                                   \
  if ((c) == 2)      asm volatile("s_waitcnt vmcnt(%0)" ::"n"(2 * LH) : "memory"); \
  else if ((c) == 1) asm volatile("s_waitcnt vmcnt(%0)" ::"n"(LH) : "memory");     \
  else               asm volatile("s_waitcnt vmcnt(0)" ::: "memory");

  const int rowA0 = wm * (BM / WM) + l15;
  const int rowB0 = wn * (BN / WN) + l15;

  bf16x8 af[FM / 2], bf[FN];
  f32x4 acc[FM][FN] = {};

  // prologue: stage halves 0,1,2; wait half 0
#pragma unroll
  for (int h = 0; h < 3; h++) {
    stageA(h, 0); stageA(h, 1);
    stageB(h, 0); if (LB > 1) stageB(h, 1);
  }
  asm volatile("s_waitcnt vmcnt(%0)" ::"n"(2 * LH) : "memory");
  __builtin_amdgcn_s_barrier();

  for (int t = 0; t < NT; t++) {
    const int s0 = (2 * t) & 3, s1 = (2 * t + 1) & 3;
    const int h3 = 2 * t + 3, h4 = 2 * t + 4;
    const bool v2 = (2 * t + 2) < H, v3 = h3 < H, v4 = h4 < H;

    // ---- P0: kc0, m-half 0
#pragma unroll
    for (int f = 0; f < FM / 2; f++) af[f] = lda(s0, rowA0 + f * 16);
#pragma unroll
    for (int g = 0; g < FN; g++) bf[g] = ldb(s0, rowB0 + g * 16);
    if (v3) { stageA(h3, 0); stageA(h3, 1); }
    __builtin_amdgcn_s_barrier();
    __builtin_amdgcn_s_setprio(1);
#pragma unroll
    for (int f = 0; f < FM / 2; f++)
#pragma unroll
      for (int g = 0; g < FN; g++) acc[f][g] = mfma16x16(af[f], bf[g], acc[f][g]);
    __builtin_amdgcn_s_setprio(0);

    // ---- P1: kc0, m-half 1 (reuse bf)
#pragma unroll
    for (int f = 0; f < FM / 2; f++) af[f] = lda(s0, rowA0 + (FM / 2 + f) * 16);
    if (v3) { stageB(h3, 0); if (LB > 1) stageB(h3, 1); }
    __builtin_amdgcn_s_barrier();
    __builtin_amdgcn_s_setprio(1);
#pragma unroll
    for (int f = 0; f < FM / 2; f++)
#pragma unroll
      for (int g = 0; g < FN; g++)
        acc[FM / 2 + f][g] = mfma16x16(af[f], bf[g], acc[FM / 2 + f][g]);
    __builtin_amdgcn_s_setprio(0);
    { const int c = (int)v2 + (int)v3; VMCNT_C2(c) }
    __builtin_amdgcn_s_barrier();  // half 2t+1 ready

    // ---- P2: kc1, m-half 0
#pragma unroll
    for (int f = 0; f < FM / 2; f++) af[f] = lda(s1, rowA0 + f * 16);
#pragma unroll
    for (int g = 0; g < FN; g++) bf[g] = ldb(s1, rowB0 + g * 16);
    if (v4) { stageA(h4, 0); stageA(h4, 1); }
    __builtin_amdgcn_s_barrier();
    __builtin_amdgcn_s_setprio(1);
#pragma unroll
    for (int f = 0; f < FM / 2; f++)
#pragma unroll
      for (int g = 0; g < FN; g++) acc[f][g] = mfma16x16(af[f], bf[g], acc[f][g]);
    __builtin_amdgcn_s_setprio(0);

    // ---- P3: kc1, m-half 1
#pragma unroll
    for (int f = 0; f < FM / 2; f++) af[f] = lda(s1, rowA0 + (FM / 2 + f) * 16);
    if (v4) { stageB(h4, 0); if (LB > 1) stageB(h4, 1); }
    __builtin_amdgcn_s_barrier();
    __builtin_amdgcn_s_setprio(1);
#pragma unroll
    for (int f = 0; f < FM / 2; f++)
#pragma unroll
      for (int g = 0; g < FN; g++)
        acc[FM / 2 + f][g] = mfma16x16(af[f], bf[g], acc[FM / 2 + f][g]);
    __builtin_amdgcn_s_setprio(0);
    { const int c = (int)v3 + (int)v4; VMCNT_C2(c) }
    __builtin_amdgcn_s_barrier();  // half 2t+2 ready
  }
#undef VMCNT_C2

  // epilogue: C layout col=l15, row=kg*4+j per 16x16 frag
  const int orow = m0 + wm * (BM / WM) + kg * 4;
#pragma unroll
  for (int fm = 0; fm < FM; fm++) {
#pragma unroll
    for (int fn = 0; fn < FN; fn++) {
      const int col = n0 + wn * (BN / WN) + fn * 16 + l15;
#pragma unroll
      for (int j = 0; j < 4; j++) {
        const size_t off = (size_t)(orow + fm * 16 + j) * N + col;
        if (OUTF32)
          ((float*)Cp)[off] = acc[fm][fn][j];
        else
          ((unsigned short*)Cp)[off] = f2bf(acc[fm][fn][j]);
      }
    }
  }
}

// ---------------------------------------------------------------- RoPE in-place on QKV (Q + K parts)
__global__ __launch_bounds__(256) void k_rope(unsigned short* __restrict__ qkv,
                                              const float* __restrict__ ctab,
                                              const float* __restrict__ stab) {
  const int idx = blockIdx.x * 256 + threadIdx.x;  // 4096*1280 total, exact
  const int row = idx / 1280;
  const int r = idx - row * 1280;
  const int head = r >> 5, pair = r & 31;
  const int s = row & 1023;
  const int col = (head < 32) ? (head * 64 + pair * 2) : (2048 + (head - 32) * 64 + pair * 2);
  const float c = ctab[s * 32 + pair], sn = stab[s * 32 + pair];
  const size_t base = (size_t)row * 3072 + col;
  const float e = bf2f(qkv[base]), o = bf2f(qkv[base + 1]);
  qkv[base]     = f2bf(e * c - o * sn);
  qkv[base + 1] = f2bf(e * sn + o * c);
}

// ---------------------------------------------------------------- V -> VT  [ (b*8+kh)*64 + d ][ s ]
__global__ __launch_bounds__(256) void k_vt(const unsigned short* __restrict__ qkv,
                                            unsigned short* __restrict__ vt) {
  __shared__ unsigned short t[32][33];
  const int st0 = blockIdx.x * 32;
  const int d0 = blockIdx.y * 32;
  const int bkh = blockIdx.z;  // b*8+kh
  const int b = bkh >> 3, kh = bkh & 7;
  const int tx = threadIdx.x & 31, ty = threadIdx.x >> 5;
#pragma unroll
  for (int i = 0; i < 4; i++) {
    int s = st0 + ty + i * 8;
    t[ty + i * 8][tx] = qkv[(size_t)(b * 1024 + s) * 3072 + 2560 + kh * 64 + d0 + tx];
  }
  __syncthreads();
#pragma unroll
  for (int i = 0; i < 4; i++) {
    int d = d0 + ty + i * 8;
    vt[(size_t)(bkh * 64 + d) * 1024 + st0 + tx] = t[tx][ty + i * 8];
  }
}

// ---------------------------------------------------------------- flash attention (causal, GQA)
// grid: 2048 blocks; qt = 15 - (bid>>7) so heavy blocks dispatch first; hb = bid&127.
// 4 waves share K/V LDS staging (double-buffered, XOR-swizzled, global_load_lds).
// Q pre-scaled by 0.125*log2e; softmax in exp2 domain; masked tile split out;
// T13 defer-max; T5 setprio around MFMA clusters.
__global__ __launch_bounds__(256) void k_attn(const unsigned short* __restrict__ qkv,
                                              const unsigned short* __restrict__ vt,
                                              unsigned short* __restrict__ ao) {
  __shared__ __align__(16) unsigned short Ks[2][64 * 64];
  __shared__ __align__(16) unsigned short Vs[2][64 * 64];
  __shared__ __align__(16) unsigned short P[4][16][72];  // per-wave P scratch

  const int bid = blockIdx.x;
  const int qt = 15 - (bid >> 7);
  const int hb = bid & 127;
  const int h = hb & 31, b = hb >> 5;
  const int q0 = qt << 6;
  const int wid = threadIdx.x >> 6, lane = threadIdx.x & 63;
  const int l15 = lane & 15, kg = lane >> 4;
  const int kh = h >> 2;
  const int qbase = b * 1024 + q0 + wid * 16;
  const int nt = qt + 1;
  const float NEGINF = -__builtin_inff();

  // Q fragments, pre-scaled by 1/sqrt(64) * log2(e) (softmax done in exp2 domain)
  bf16x8 aq0, aq1;
  {
    const size_t qoff = (size_t)(qbase + l15) * 3072 + h * 64 + kg * 8;
    aq0 = *(const bf16x8*)&qkv[qoff];
    aq1 = *(const bf16x8*)&qkv[qoff + 32];
#pragma unroll
    for (int i = 0; i < 8; i++) {
      aq0[i] = (__bf16)((float)aq0[i] * 0.18033688011112042f);
      aq1[i] = (__bf16)((float)aq1[i] * 0.18033688011112042f);
    }
  }

  // staging geometry: lane l stages row (l>>3), 16B slot (l&7); source col is
  // inverse-XOR-swizzled so that the swizzled LDS read below sees linear data.
  const int l8 = lane >> 3;
  const int colel = ((lane & 7) ^ l8) * 8;  // element offset, pre-swizzled
  const size_t krowbase = (size_t)(b * 1024) * 3072 + 2048 + kh * 64 + colel;
  const size_t vrowbase = (size_t)((b * 8 + kh) * 64) * 1024 + colel;

  // prologue: stage tile 0
#pragma unroll
  for (int i = 0; i < 2; i++) {
    const int r = wid * 16 + i * 8 + l8;
    load16_lds(&qkv[krowbase + (size_t)r * 3072], &Ks[0][(wid * 16 + i * 8) * 64]);
    load16_lds(&vt[vrowbase + (size_t)r * 1024], &Vs[0][(wid * 16 + i * 8) * 64]);
  }
  asm volatile("s_waitcnt vmcnt(0)" ::: "memory");
  __builtin_amdgcn_s_barrier();

  f32x4 o[4] = {};
  float mrow[4] = {NEGINF, NEGINF, NEGINF, NEGINF};
  float lrow[4] = {0.f, 0.f, 0.f, 0.f};

  const int swz = (l15 & 7) * 8;  // read-side XOR swizzle (elements)

  for (int t = 0; t < nt; t++) {
    const int cur = t & 1;
    // prefetch next tile into the other buffer (stays in flight during compute)
    if (t + 1 < nt) {
      const size_t kv1 = (size_t)((t + 1) << 6);
#pragma unroll
      for (int i = 0; i < 2; i++) {
        const int r = wid * 16 + i * 8 + l8;
        load16_lds(&qkv[krowbase + (kv1 + r) * 3072], &Ks[cur ^ 1][(wid * 16 + i * 8) * 64]);
        load16_lds(&vt[vrowbase + (size_t)r * 1024 + kv1], &Vs[cur ^ 1][(wid * 16 + i * 8) * 64]);
      }
    }
    const int kv0 = t << 6;

    // QK^T from swizzled LDS
    f32x4 sc[4] = {};
    __builtin_amdgcn_s_setprio(1);
#pragma unroll
    for (int ct = 0; ct < 4; ct++) {
      const unsigned short* kr = &Ks[cur][(ct * 16 + l15) * 64];
      bf16x8 bk0 = *(const bf16x8*)&kr[(kg * 8) ^ swz];
      bf16x8 bk1 = *(const bf16x8*)&kr[(kg * 8 + 32) ^ swz];
      sc[ct] = mfma16x16(aq0, bk0, sc[ct]);
      sc[ct] = mfma16x16(aq1, bk1, sc[ct]);
    }
    __builtin_amdgcn_s_setprio(0);

    // p[ct][reg]: scores in exp2 domain; mask only on the diagonal tile
    float p[4][4];
    if (t == qt) {
#pragma unroll
      for (int reg = 0; reg < 4; reg++) {
        const int rowg = q0 + wid * 16 + kg * 4 + reg;
#pragma unroll
        for (int ct = 0; ct < 4; ct++) {
          const int colg = kv0 + ct * 16 + l15;
          p[ct][reg] = (colg > rowg) ? NEGINF : sc[ct][reg];
        }
      }
    } else {
#pragma unroll
      for (int reg = 0; reg < 4; reg++)
#pragma unroll
        for (int ct = 0; ct < 4; ct++) p[ct][reg] = sc[ct][reg];
    }

    // row maxima (rows = kg*4+reg; reduce over l15 groups)
    float rm[4];
#pragma unroll
    for (int reg = 0; reg < 4; reg++) {
      float v = fmaxf(fmaxf(p[0][reg], p[1][reg]), fmaxf(p[2][reg], p[3][reg]));
#pragma unroll
      for (int off = 1; off < 16; off <<= 1) v = fmaxf(v, __shfl_xor(v, off));
      rm[reg] = v;
    }

    const int okl = (rm[0] <= mrow[0] + 8.f) && (rm[1] <= mrow[1] + 8.f) &&
                    (rm[2] <= mrow[2] + 8.f) && (rm[3] <= mrow[3] + 8.f);
    if (__all(okl)) {
      // deferred: keep old max, no rescale (P bounded by 2^8)
#pragma unroll
      for (int reg = 0; reg < 4; reg++) {
        float rs = 0.f;
#pragma unroll
        for (int ct = 0; ct < 4; ct++) {
          const float e = exp2f(p[ct][reg] - mrow[reg]);
          p[ct][reg] = e;
          rs += e;
        }
#pragma unroll
        for (int off = 1; off < 16; off <<= 1) rs += __shfl_xor(rs, off);
        lrow[reg] += rs;
      }
    } else {
      float fac[4];
#pragma unroll
      for (int reg = 0; reg < 4; reg++) {
        const float mnew = fmaxf(mrow[reg], rm[reg]);
        fac[reg] = exp2f(mrow[reg] - mnew);  // -inf - finite -> 0
        float rs = 0.f;
#pragma unroll
        for (int ct = 0; ct < 4; ct++) {
          const float e = exp2f(p[ct][reg] - mnew);
          p[ct][reg] = e;
          rs += e;
        }
#pragma unroll
        for (int off = 1; off < 16; off <<= 1) rs += __shfl_xor(rs, off);
        lrow[reg] = lrow[reg] * fac[reg] + rs;
        mrow[reg] = mnew;
      }
#pragma unroll
      for (int ct = 0; ct < 4; ct++) {
        o[ct][0] *= fac[0]; o[ct][1] *= fac[1]; o[ct][2] *= fac[2]; o[ct][3] *= fac[3];
      }
    }

    // P tile to wave-private LDS (true coordinates), then read back as A-fragments
#pragma unroll
    for (int reg = 0; reg < 4; reg++)
#pragma unroll
      for (int ct = 0; ct < 4; ct++)
        P[wid][kg * 4 + reg][ct * 16 + l15] = f2bf(p[ct][reg]);

    bf16x8 ap0 = *(const bf16x8*)&P[wid][l15][kg * 8];
    bf16x8 ap1 = *(const bf16x8*)&P[wid][l15][32 + kg * 8];

    // PV from swizzled LDS (Vs rows are d, cols are s)
    __builtin_amdgcn_s_setprio(1);
#pragma unroll
    for (int ct = 0; ct < 4; ct++) {
      const unsigned short* vr = &Vs[cur][(ct * 16 + l15) * 64];
      bf16x8 bv0 = *(const bf16x8*)&vr[(kg * 8) ^ swz];
      bf16x8 bv1 = *(const bf16x8*)&vr[(kg * 8 + 32) ^ swz];
      o[ct] = mfma16x16(ap0, bv0, o[ct]);
      o[ct] = mfma16x16(ap1, bv1, o[ct]);
    }
    __builtin_amdgcn_s_setprio(0);

    // next tile's staging must be complete, and all waves done reading cur,
    // before cur^1 is consumed / cur is overwritten next iteration.
    asm volatile("s_waitcnt vmcnt(0)" ::: "memory");
    __builtin_amdgcn_s_barrier();
  }

  // epilogue: divide by l, write bf16
#pragma unroll
  for (int ct = 0; ct < 4; ct++) {
#pragma unroll
    for (int reg = 0; reg < 4; reg++) {
      const float val = o[ct][reg] / lrow[reg];
      ao[(size_t)(qbase + kg * 4 + reg) * 2048 + h * 64 + ct * 16 + l15] = f2bf(val);
    }
  }
}

// ---------------------------------------------------------------- launcher
extern "C" void kernel_launch(void* const* d_in, const int* in_sizes, int n_in,
                              void* d_out, int out_size, void* d_ws, size_t ws_size,
                              hipStream_t stream) {
  const float* x    = (const float*)d_in[0];
  const float* pcos = (const float*)d_in[1];
  const float* psin = (const float*)d_in[2];
  const float* wq   = (const float*)d_in[3];
  const float* wk   = (const float*)d_in[4];
  const float* wv   = (const float*)d_in[5];
  const float* wo   = (const float*)d_in[6];

  char* ws = (char*)d_ws;
  unsigned short* XB  = (unsigned short*)(ws);              // 4096x2048 bf16 (x, later attn-out)
  unsigned short* WT  = (unsigned short*)(ws + 16777216);   // 3072x2048 bf16 (wq|wk|wv)^T
  unsigned short* WOT = (unsigned short*)(ws + 29360128);   // 2048x2048 bf16 wo^T
  unsigned short* QKV = (unsigned short*)(ws + 37748736);   // 4096x3072 bf16
  unsigned short* VT  = (unsigned short*)(ws + 62914560);   // (4*8*64)x1024 bf16
  // total 64 MiB

  k_convert_x<<<8192, 256, 0, stream>>>(x, XB, 8388608);
  k_transpose_w<<<dim3(64, 64), 256, 0, stream>>>(wq, WT, 2048);
  k_transpose_w<<<dim3(16, 64), 256, 0, stream>>>(wk, WT + (size_t)2048 * 2048, 512);
  k_transpose_w<<<dim3(16, 64), 256, 0, stream>>>(wv, WT + (size_t)2560 * 2048, 512);
  k_transpose_w<<<dim3(64, 64), 256, 0, stream>>>(wo, WOT, 2048);

  k_gemm8<0, 256, 2, 4><<<192, 512, 0, stream>>>(XB, WT, QKV, 4096, 3072, 2048);
  k_rope<<<20480, 256, 0, stream>>>(QKV, pcos, psin);
  k_vt<<<dim3(32, 2, 32), 256, 0, stream>>>(QKV, VT);
  k_attn<<<2048, 256, 0, stream>>>(QKV, VT, XB);
  k_gemm8<1, 128, 4, 2><<<256, 512, 0, stream>>>(XB, WOT, d_out, 4096, 2048, 2048);
}

// Round 5
// 277.936 us; speedup vs baseline: 1.8662x; 1.0877x over previous
//
#include <hip/hip_runtime.h>
#include <hip/hip_bf16.h>

// Problem constants
// B=4, S=1024, D=2048, NH=32, NKV=8, HD=64, HALF=32, N_REP=4
// ROWS = B*S = 4096 ; QKV cols = 2048 + 512 + 512 = 3072

typedef __bf16 bf16x8 __attribute__((ext_vector_type(8)));
typedef float  f32x4  __attribute__((ext_vector_type(4)));
typedef unsigned short u16x8 __attribute__((ext_vector_type(8)));

#define DEV static __device__ __forceinline__

DEV unsigned short f2bf(float f) {
  __hip_bfloat16 h = __float2bfloat16(f);
  unsigned short u;
  __builtin_memcpy(&u, &h, 2);
  return u;
}
DEV float bf2f(unsigned short u) {
  unsigned int ui = ((unsigned int)u) << 16;
  float f;
  __builtin_memcpy(&f, &ui, 4);
  return f;
}

typedef const unsigned int __attribute__((address_space(1)))* as1_u32cp;
typedef unsigned int __attribute__((address_space(3)))* as3_u32p;

// async global->LDS, 16B per lane. lds dest must be wave-uniform base; HW adds lane*16.
DEV void load16_lds(const unsigned short* g, unsigned short* l) {
  __builtin_amdgcn_global_load_lds((as1_u32cp)(unsigned long long)g,
                                   (as3_u32p)(unsigned int)(unsigned long long)l,
                                   16, 0, 0);
}

DEV f32x4 mfma16x16(bf16x8 a, bf16x8 b, f32x4 c) {
  return __builtin_amdgcn_mfma_f32_16x16x32_bf16(a, b, c, 0, 0, 0);
}

// ---------------------------------------------------------------- convert x -> bf16
__global__ __launch_bounds__(256) void k_convert_x(const float* __restrict__ x,
                                                   unsigned short* __restrict__ xb, int n) {
  int i = (blockIdx.x * 256 + threadIdx.x) * 4;
  if (i < n) {
    float4 v = *(const float4*)(x + i);
    ushort4 o;
    o.x = f2bf(v.x); o.y = f2bf(v.y); o.z = f2bf(v.z); o.w = f2bf(v.w);
    *(ushort4*)(xb + i) = o;
  }
}

// --------------------------------------------------- transpose fp32 [2048][N] -> bf16 [N][2048]
__global__ __launch_bounds__(256) void k_transpose_w(const float* __restrict__ src,
                                                     unsigned short* __restrict__ dst, int N) {
  __shared__ float t[32][33];
  const int n0 = blockIdx.x * 32, k0 = blockIdx.y * 32;
  const int tx = threadIdx.x & 31, ty = threadIdx.x >> 5;  // ty 0..7
#pragma unroll
  for (int i = 0; i < 4; i++) {
    int k = k0 + ty + i * 8;
    t[ty + i * 8][tx] = src[(size_t)k * N + n0 + tx];
  }
  __syncthreads();
#pragma unroll
  for (int i = 0; i < 4; i++) {
    int n = n0 + ty + i * 8;
    dst[(size_t)n * 2048 + k0 + tx] = f2bf(t[tx][ty + i * 8]);
  }
}

// ---------------------------------------------------------------- GEMM  C = A[M][K] * Bt[N][K]^T
// 256xBN tile, K processed in 32-col halves, 4 LDS slots per operand (depth-3 prefetch).
// 8 waves (WM x WN). Per tile (=2 halves): 4 phases, each {ds_read frags; issue 2 stage
// loads; barrier; setprio MFMA}; counted vmcnt at pair ends only (T3+T4), T2 swizzle
// slot^=(row>>1)&3 with inverse-swizzled global source, T5 setprio.
template <int OUTF32, int BN, int WM, int WN>
__global__ __launch_bounds__(512) void k_gemm8(const unsigned short* __restrict__ A,
                                               const unsigned short* __restrict__ Bt,
                                               void* __restrict__ Cp, int M, int N, int K) {
  constexpr int BM = 256;
  constexpr int FM = BM / WM / 16;  // m-frags per wave
  constexpr int FN = BN / WN / 16;  // n-frags per wave
  constexpr int LA = BM * 4 / 512;  // A stage loads per thread per half (2)
  constexpr int LB = BN * 4 / 512;  // B stage loads per thread per half (2 or 1)
  constexpr int LH = LA + LB;
  __shared__ __align__(16) unsigned short As[4][BM * 32];
  __shared__ __align__(16) unsigned short Bs[4][BN * 32];

  const int nbx = N / BN;
  const int nwg = gridDim.x;
  int wg = blockIdx.x;
  wg = (wg & 7) * (nwg >> 3) + (wg >> 3);  // XCD swizzle (nwg % 8 == 0 here)
  const int bx = wg % nbx, by = wg / nbx;
  const int m0 = by << 8, n0 = bx * BN;
  const int tid = threadIdx.x;
  const int lane = tid & 63, wid = tid >> 6;
  const int wm = wid / WN, wn = wid % WN;
  const int l15 = lane & 15, kg = lane >> 4;
  const int H = K >> 5;   // 32-col halves
  const int NT = K >> 6;  // 64-col tiles

  // staging: slot-unit u = i*512 + tid; row = u>>2, slot16B = u&3; global col
  // inverse-swizzled so linear LDS + XOR read line up.
  auto stageA = [&](int h, int i) {
    const int u = i * 512 + tid;
    const int row = u >> 2, sl = u & 3;
    const int gc = ((sl ^ ((row >> 1) & 3)) << 3);
    load16_lds(&A[(size_t)(m0 + row) * K + (h << 5) + gc],
               &As[h & 3][(i * 512 + (tid & ~63)) * 8]);
  };
  auto stageB = [&](int h, int i) {
    const int u = i * 512 + tid;
    const int row = u >> 2, sl = u & 3;
    const int gc = ((sl ^ ((row >> 1) & 3)) << 3);
    load16_lds(&Bt[(size_t)(n0 + row) * K + (h << 5) + gc],
               &Bs[h & 3][(i * 512 + (tid & ~63)) * 8]);
  };
  auto lda = [&](int s, int r) {
    return *(const bf16x8*)&As[s][r * 32 + ((kg ^ ((r >> 1) & 3)) << 3)];
  };
  auto ldb = [&](int s, int r) {
    return *(const bf16x8*)&Bs[s][r * 32 + ((kg ^ ((r >> 1) & 3)) << 3)];
  };

#define VMCNT_C2(c)                                                   \
  if ((c) == 2)      asm volatile("s_waitcnt vmcnt(%0)" ::"n"(2 * LH) : "memory"); \
  else if ((c) == 1) asm volatile("s_waitcnt vmcnt(%0)" ::"n"(LH) : "memory");     \
  else               asm volatile("s_waitcnt vmcnt(0)" ::: "memory");

  const int rowA0 = wm * (BM / WM) + l15;
  const int rowB0 = wn * (BN / WN) + l15;

  bf16x8 af[FM / 2], bf[FN];
  f32x4 acc[FM][FN] = {};

  // prologue: stage halves 0,1,2; wait half 0
#pragma unroll
  for (int h = 0; h < 3; h++) {
    stageA(h, 0); stageA(h, 1);
    stageB(h, 0); if (LB > 1) stageB(h, 1);
  }
  asm volatile("s_waitcnt vmcnt(%0)" ::"n"(2 * LH) : "memory");
  __builtin_amdgcn_s_barrier();

  for (int t = 0; t < NT; t++) {
    const int s0 = (2 * t) & 3, s1 = (2 * t + 1) & 3;
    const int h3 = 2 * t + 3, h4 = 2 * t + 4;
    const bool v2 = (2 * t + 2) < H, v3 = h3 < H, v4 = h4 < H;

    // ---- P0: kc0, m-half 0
#pragma unroll
    for (int f = 0; f < FM / 2; f++) af[f] = lda(s0, rowA0 + f * 16);
#pragma unroll
    for (int g = 0; g < FN; g++) bf[g] = ldb(s0, rowB0 + g * 16);
    if (v3) { stageA(h3, 0); stageA(h3, 1); }
    __builtin_amdgcn_s_barrier();
    __builtin_amdgcn_s_setprio(1);
#pragma unroll
    for (int f = 0; f < FM / 2; f++)
#pragma unroll
      for (int g = 0; g < FN; g++) acc[f][g] = mfma16x16(af[f], bf[g], acc[f][g]);
    __builtin_amdgcn_s_setprio(0);

    // ---- P1: kc0, m-half 1 (reuse bf)
#pragma unroll
    for (int f = 0; f < FM / 2; f++) af[f] = lda(s0, rowA0 + (FM / 2 + f) * 16);
    if (v3) { stageB(h3, 0); if (LB > 1) stageB(h3, 1); }
    __builtin_amdgcn_s_barrier();
    __builtin_amdgcn_s_setprio(1);
#pragma unroll
    for (int f = 0; f < FM / 2; f++)
#pragma unroll
      for (int g = 0; g < FN; g++)
        acc[FM / 2 + f][g] = mfma16x16(af[f], bf[g], acc[FM / 2 + f][g]);
    __builtin_amdgcn_s_setprio(0);
    { const int c = (int)v2 + (int)v3; VMCNT_C2(c) }
    __builtin_amdgcn_s_barrier();  // half 2t+1 ready

    // ---- P2: kc1, m-half 0
#pragma unroll
    for (int f = 0; f < FM / 2; f++) af[f] = lda(s1, rowA0 + f * 16);
#pragma unroll
    for (int g = 0; g < FN; g++) bf[g] = ldb(s1, rowB0 + g * 16);
    if (v4) { stageA(h4, 0); stageA(h4, 1); }
    __builtin_amdgcn_s_barrier();
    __builtin_amdgcn_s_setprio(1);
#pragma unroll
    for (int f = 0; f < FM / 2; f++)
#pragma unroll
      for (int g = 0; g < FN; g++) acc[f][g] = mfma16x16(af[f], bf[g], acc[f][g]);
    __builtin_amdgcn_s_setprio(0);

    // ---- P3: kc1, m-half 1
#pragma unroll
    for (int f = 0; f < FM / 2; f++) af[f] = lda(s1, rowA0 + (FM / 2 + f) * 16);
    if (v4) { stageB(h4, 0); if (LB > 1) stageB(h4, 1); }
    __builtin_amdgcn_s_barrier();
    __builtin_amdgcn_s_setprio(1);
#pragma unroll
    for (int f = 0; f < FM / 2; f++)
#pragma unroll
      for (int g = 0; g < FN; g++)
        acc[FM / 2 + f][g] = mfma16x16(af[f], bf[g], acc[FM / 2 + f][g]);
    __builtin_amdgcn_s_setprio(0);
    { const int c = (int)v3 + (int)v4; VMCNT_C2(c) }
    __builtin_amdgcn_s_barrier();  // half 2t+2 ready
  }
#undef VMCNT_C2

  // epilogue: C layout col=l15, row=kg*4+j per 16x16 frag
  const int orow = m0 + wm * (BM / WM) + kg * 4;
#pragma unroll
  for (int fm = 0; fm < FM; fm++) {
#pragma unroll
    for (int fn = 0; fn < FN; fn++) {
      const int col = n0 + wn * (BN / WN) + fn * 16 + l15;
#pragma unroll
      for (int j = 0; j < 4; j++) {
        const size_t off = (size_t)(orow + fm * 16 + j) * N + col;
        if (OUTF32)
          ((float*)Cp)[off] = acc[fm][fn][j];
        else
          ((unsigned short*)Cp)[off] = f2bf(acc[fm][fn][j]);
      }
    }
  }
}

// ---------------------------------------------------------------- RoPE in-place on QKV (Q + K parts)
// vectorized: one thread = 4 pairs (8 bf16, 16B). total 4096 rows * 320 quads.
__global__ __launch_bounds__(256) void k_rope(unsigned short* __restrict__ qkv,
                                              const float* __restrict__ ctab,
                                              const float* __restrict__ stab) {
  const int idx = blockIdx.x * 256 + threadIdx.x;
  const int row = idx / 320;
  const int r = idx - row * 320;
  const int head = r >> 3, quad = r & 7;
  const int s = row & 1023;
  const int col = ((head < 32) ? head * 64 : 2048 + (head - 32) * 64) + quad * 8;
  const float4 c = *(const float4*)&ctab[s * 32 + quad * 4];
  const float4 sn = *(const float4*)&stab[s * 32 + quad * 4];
  const size_t base = (size_t)row * 3072 + col;
  u16x8 v = *(const u16x8*)&qkv[base];
  const float cc[4] = {c.x, c.y, c.z, c.w};
  const float ss[4] = {sn.x, sn.y, sn.z, sn.w};
#pragma unroll
  for (int i = 0; i < 4; i++) {
    const float e = bf2f(v[2 * i]), o = bf2f(v[2 * i + 1]);
    v[2 * i]     = f2bf(e * cc[i] - o * ss[i]);
    v[2 * i + 1] = f2bf(e * ss[i] + o * cc[i]);
  }
  *(u16x8*)&qkv[base] = v;
}

// ---------------------------------------------------------------- V -> VT  [ (b*8+kh)*64 + d ][ s ]
__global__ __launch_bounds__(256) void k_vt(const unsigned short* __restrict__ qkv,
                                            unsigned short* __restrict__ vt) {
  __shared__ unsigned short t[32][33];
  const int st0 = blockIdx.x * 32;
  const int d0 = blockIdx.y * 32;
  const int bkh = blockIdx.z;  // b*8+kh
  const int b = bkh >> 3, kh = bkh & 7;
  const int tx = threadIdx.x & 31, ty = threadIdx.x >> 5;
#pragma unroll
  for (int i = 0; i < 4; i++) {
    int s = st0 + ty + i * 8;
    t[ty + i * 8][tx] = qkv[(size_t)(b * 1024 + s) * 3072 + 2560 + kh * 64 + d0 + tx];
  }
  __syncthreads();
#pragma unroll
  for (int i = 0; i < 4; i++) {
    int d = d0 + ty + i * 8;
    vt[(size_t)(bkh * 64 + d) * 1024 + st0 + tx] = t[tx][ty + i * 8];
  }
}

// ---------------------------------------------------------------- flash attention (causal, GQA)
// Swapped-operand structure: sc = mfma(K,Q) -> S^T[k][q], q = l15 lane-local, so
// softmax max/sum are lane-local trees + 2 shfl (kg axis). PV also swapped:
// o = mfma(V^T, P) -> O^T[d][q]; rescale fac and 1/l are per-lane scalars.
// 4 waves share K/V LDS staging (double-buffered, XOR-swizzled, global_load_lds).
// LDS = 40960 B exactly -> 4 blocks/CU.
__global__ __launch_bounds__(256) void k_attn(const unsigned short* __restrict__ qkv,
                                              const unsigned short* __restrict__ vt,
                                              unsigned short* __restrict__ ao) {
  __shared__ __align__(16) unsigned short Ks[2][64 * 64];
  __shared__ __align__(16) unsigned short Vs[2][64 * 64];
  __shared__ __align__(16) unsigned short P[4][16][64];  // per-wave, k-XOR-swizzled

  const int bid = blockIdx.x;
  const int qt = 15 - (bid >> 7);
  const int hb = bid & 127;
  const int h = hb & 31, b = hb >> 5;
  const int q0 = qt << 6;
  const int wid = threadIdx.x >> 6, lane = threadIdx.x & 63;
  const int l15 = lane & 15, kg = lane >> 4;
  const int kh = h >> 2;
  const int qbase = b * 1024 + q0 + wid * 16;
  const int nt = qt + 1;
  const float NEGINF = -__builtin_inff();

  // Q fragments, pre-scaled by 1/sqrt(64) * log2(e) (softmax in exp2 domain)
  bf16x8 aq0, aq1;
  {
    const size_t qoff = (size_t)(qbase + l15) * 3072 + h * 64 + kg * 8;
    aq0 = *(const bf16x8*)&qkv[qoff];
    aq1 = *(const bf16x8*)&qkv[qoff + 32];
#pragma unroll
    for (int i = 0; i < 8; i++) {
      aq0[i] = (__bf16)((float)aq0[i] * 0.18033688011112042f);
      aq1[i] = (__bf16)((float)aq1[i] * 0.18033688011112042f);
    }
  }

  // staging geometry: lane l stages row (l>>3), 16B slot (l&7); source col is
  // inverse-XOR-swizzled so that the swizzled LDS read below sees linear data.
  const int l8 = lane >> 3;
  const int colel = ((lane & 7) ^ l8) * 8;  // element offset, pre-swizzled
  const size_t krowbase = (size_t)(b * 1024) * 3072 + 2048 + kh * 64 + colel;
  const size_t vrowbase = (size_t)((b * 8 + kh) * 64) * 1024 + colel;

  // prologue: stage tile 0
#pragma unroll
  for (int i = 0; i < 2; i++) {
    const int r = wid * 16 + i * 8 + l8;
    load16_lds(&qkv[krowbase + (size_t)r * 3072], &Ks[0][(wid * 16 + i * 8) * 64]);
    load16_lds(&vt[vrowbase + (size_t)r * 1024], &Vs[0][(wid * 16 + i * 8) * 64]);
  }
  asm volatile("s_waitcnt vmcnt(0)" ::: "memory");
  __builtin_amdgcn_s_barrier();

  f32x4 o[4] = {};
  float mrow = NEGINF;  // running max for q = l15 (replicated across kg)
  float lrow = 0.f;     // running sum for q = l15

  const int swz = (l15 & 7) * 8;  // read-side XOR swizzle for K/V tiles (elements)
  const int psw = (l15 & 7) * 8;  // P k-swizzle (same form)

  for (int t = 0; t < nt; t++) {
    const int cur = t & 1;
    // prefetch next tile into the other buffer (stays in flight during compute)
    if (t + 1 < nt) {
      const size_t kv1 = (size_t)((t + 1) << 6);
#pragma unroll
      for (int i = 0; i < 2; i++) {
        const int r = wid * 16 + i * 8 + l8;
        load16_lds(&qkv[krowbase + (kv1 + r) * 3072], &Ks[cur ^ 1][(wid * 16 + i * 8) * 64]);
        load16_lds(&vt[vrowbase + (size_t)r * 1024 + kv1], &Vs[cur ^ 1][(wid * 16 + i * 8) * 64]);
      }
    }

    // QK^T (swapped): sc[ct] = K_frag * Q^T -> S^T[k = ct*16+kg*4+reg][q = l15]
    f32x4 sc[4] = {};
    __builtin_amdgcn_s_setprio(1);
#pragma unroll
    for (int ct = 0; ct < 4; ct++) {
      const unsigned short* kr = &Ks[cur][(ct * 16 + l15) * 64];
      bf16x8 bk0 = *(const bf16x8*)&kr[(kg * 8) ^ swz];
      bf16x8 bk1 = *(const bf16x8*)&kr[(kg * 8 + 32) ^ swz];
      sc[ct] = mfma16x16(bk0, aq0, sc[ct]);
      sc[ct] = mfma16x16(bk1, aq1, sc[ct]);
    }
    __builtin_amdgcn_s_setprio(0);

    // scores for this lane's q (= l15): 16 values over k
    float p[4][4];
    if (t == qt) {
      const int qloc = wid * 16 + l15;  // local q within 64-tile (kv0 == q0)
#pragma unroll
      for (int ct = 0; ct < 4; ct++)
#pragma unroll
        for (int reg = 0; reg < 4; reg++) {
          const int kloc = ct * 16 + kg * 4 + reg;
          p[ct][reg] = (kloc > qloc) ? NEGINF : sc[ct][reg];
        }
    } else {
#pragma unroll
      for (int ct = 0; ct < 4; ct++)
#pragma unroll
        for (int reg = 0; reg < 4; reg++) p[ct][reg] = sc[ct][reg];
    }

    // tile max: lane-local tree + 2 shfl over kg axis
    float rm = NEGINF;
#pragma unroll
    for (int ct = 0; ct < 4; ct++)
      rm = fmaxf(rm, fmaxf(fmaxf(p[ct][0], p[ct][1]), fmaxf(p[ct][2], p[ct][3])));
    rm = fmaxf(rm, __shfl_xor(rm, 16));
    rm = fmaxf(rm, __shfl_xor(rm, 32));

    const float mnew = fmaxf(mrow, rm);
    const float fac = exp2f(mrow - mnew);  // -inf - finite -> 0
    float rs = 0.f;
#pragma unroll
    for (int ct = 0; ct < 4; ct++)
#pragma unroll
      for (int reg = 0; reg < 4; reg++) {
        const float e = exp2f(p[ct][reg] - mnew);
        p[ct][reg] = e;
        rs += e;
      }
    rs += __shfl_xor(rs, 16);
    rs += __shfl_xor(rs, 32);
    lrow = lrow * fac + rs;
    mrow = mnew;
#pragma unroll
    for (int ct = 0; ct < 4; ct++) {
      o[ct][0] *= fac; o[ct][1] *= fac; o[ct][2] *= fac; o[ct][3] *= fac;
    }

    // P[q=l15][k] to wave-private LDS, packed 4 regs = 8B, k-swizzled
#pragma unroll
    for (int ct = 0; ct < 4; ct++) {
      ushort4 pk;
      pk.x = f2bf(p[ct][0]); pk.y = f2bf(p[ct][1]);
      pk.z = f2bf(p[ct][2]); pk.w = f2bf(p[ct][3]);
      *(ushort4*)&P[wid][l15][(ct * 16 + kg * 4) ^ psw] = pk;
    }

    // read P row l15 as B-fragments (contiguous, swizzle preserved at 8-elem blocks)
    bf16x8 ap0 = *(const bf16x8*)&P[wid][l15][(kg * 8) ^ psw];
    bf16x8 ap1 = *(const bf16x8*)&P[wid][l15][(32 + kg * 8) ^ psw];

    // PV (swapped): o[ct] = V^T_frag * P -> O^T[d = ct*16+kg*4+reg][q = l15]
    __builtin_amdgcn_s_setprio(1);
#pragma unroll
    for (int ct = 0; ct < 4; ct++) {
      const unsigned short* vr = &Vs[cur][(ct * 16 + l15) * 64];
      bf16x8 bv0 = *(const bf16x8*)&vr[(kg * 8) ^ swz];
      bf16x8 bv1 = *(const bf16x8*)&vr[(kg * 8 + 32) ^ swz];
      o[ct] = mfma16x16(bv0, ap0, o[ct]);
      o[ct] = mfma16x16(bv1, ap1, o[ct]);
    }
    __builtin_amdgcn_s_setprio(0);

    // next tile's staging must be complete, and all waves done reading cur,
    // before cur^1 is consumed / cur is overwritten next iteration.
    asm volatile("s_waitcnt vmcnt(0)" ::: "memory");
    __builtin_amdgcn_s_barrier();
  }

  // epilogue: O^T[d][q]: lane writes q = qbase+l15, d = ct*16+kg*4+reg (packed 8B)
  const float rl = 1.0f / lrow;
  const size_t obase = (size_t)(qbase + l15) * 2048 + h * 64;
#pragma unroll
  for (int ct = 0; ct < 4; ct++) {
    ushort4 ov;
    ov.x = f2bf(o[ct][0] * rl); ov.y = f2bf(o[ct][1] * rl);
    ov.z = f2bf(o[ct][2] * rl); ov.w = f2bf(o[ct][3] * rl);
    *(ushort4*)&ao[obase + ct * 16 + kg * 4] = ov;
  }
}

// ---------------------------------------------------------------- launcher
extern "C" void kernel_launch(void* const* d_in, const int* in_sizes, int n_in,
                              void* d_out, int out_size, void* d_ws, size_t ws_size,
                              hipStream_t stream) {
  const float* x    = (const float*)d_in[0];
  const float* pcos = (const float*)d_in[1];
  const float* psin = (const float*)d_in[2];
  const float* wq   = (const float*)d_in[3];
  const float* wk   = (const float*)d_in[4];
  const float* wv   = (const float*)d_in[5];
  const float* wo   = (const float*)d_in[6];

  char* ws = (char*)d_ws;
  unsigned short* XB  = (unsigned short*)(ws);              // 4096x2048 bf16 (x, later attn-out)
  unsigned short* WT  = (unsigned short*)(ws + 16777216);   // 3072x2048 bf16 (wq|wk|wv)^T
  unsigned short* WOT = (unsigned short*)(ws + 29360128);   // 2048x2048 bf16 wo^T
  unsigned short* QKV = (unsigned short*)(ws + 37748736);   // 4096x3072 bf16
  unsigned short* VT  = (unsigned short*)(ws + 62914560);   // (4*8*64)x1024 bf16
  // total 64 MiB

  k_convert_x<<<8192, 256, 0, stream>>>(x, XB, 8388608);
  k_transpose_w<<<dim3(64, 64), 256, 0, stream>>>(wq, WT, 2048);
  k_transpose_w<<<dim3(16, 64), 256, 0, stream>>>(wk, WT + (size_t)2048 * 2048, 512);
  k_transpose_w<<<dim3(16, 64), 256, 0, stream>>>(wv, WT + (size_t)2560 * 2048, 512);
  k_transpose_w<<<dim3(64, 64), 256, 0, stream>>>(wo, WOT, 2048);

  k_gemm8<0, 256, 2, 4><<<192, 512, 0, stream>>>(XB, WT, QKV, 4096, 3072, 2048);
  k_rope<<<5120, 256, 0, stream>>>(QKV, pcos, psin);
  k_vt<<<dim3(32, 2, 32), 256, 0, stream>>>(QKV, VT);
  k_attn<<<2048, 256, 0, stream>>>(QKV, VT, XB);
  k_gemm8<1, 128, 4, 2><<<256, 512, 0, stream>>>(XB, WOT, d_out, 4096, 2048, 2048);
}

// Round 6
// 271.502 us; speedup vs baseline: 1.9105x; 1.0237x over previous
//
#include <hip/hip_runtime.h>
#include <hip/hip_bf16.h>

// Problem constants
// B=4, S=1024, D=2048, NH=32, NKV=8, HD=64, HALF=32, N_REP=4
// ROWS = B*S = 4096 ; QKV cols = 2048 + 512 + 512 = 3072

typedef __bf16 bf16x8 __attribute__((ext_vector_type(8)));
typedef float  f32x4  __attribute__((ext_vector_type(4)));
typedef unsigned short u16x8 __attribute__((ext_vector_type(8)));

#define DEV static __device__ __forceinline__

DEV unsigned short f2bf(float f) {
  __hip_bfloat16 h = __float2bfloat16(f);
  unsigned short u;
  __builtin_memcpy(&u, &h, 2);
  return u;
}
DEV float bf2f(unsigned short u) {
  unsigned int ui = ((unsigned int)u) << 16;
  float f;
  __builtin_memcpy(&f, &ui, 4);
  return f;
}

typedef const unsigned int __attribute__((address_space(1)))* as1_u32cp;
typedef unsigned int __attribute__((address_space(3)))* as3_u32p;

// async global->LDS, 16B per lane. lds dest must be wave-uniform base; HW adds lane*16.
DEV void load16_lds(const unsigned short* g, unsigned short* l) {
  __builtin_amdgcn_global_load_lds((as1_u32cp)(unsigned long long)g,
                                   (as3_u32p)(unsigned int)(unsigned long long)l,
                                   16, 0, 0);
}

DEV f32x4 mfma16x16(bf16x8 a, bf16x8 b, f32x4 c) {
  return __builtin_amdgcn_mfma_f32_16x16x32_bf16(a, b, c, 0, 0, 0);
}

// ---------------------------------------------------------------- convert x -> bf16
__global__ __launch_bounds__(256) void k_convert_x(const float* __restrict__ x,
                                                   unsigned short* __restrict__ xb, int n) {
  int i = (blockIdx.x * 256 + threadIdx.x) * 4;
  if (i < n) {
    float4 v = *(const float4*)(x + i);
    ushort4 o;
    o.x = f2bf(v.x); o.y = f2bf(v.y); o.z = f2bf(v.z); o.w = f2bf(v.w);
    *(ushort4*)(xb + i) = o;
  }
}

// --------------------------------------------------- fused weight transpose -> bf16 WT[3072][2048]
// region by n0: [0,2048) wq (N=2048), [2048,2560) wk (N=512), [2560,3072) wv (N=512)
__global__ __launch_bounds__(256) void k_transpose_qkv(const float* __restrict__ wq,
                                                       const float* __restrict__ wk,
                                                       const float* __restrict__ wv,
                                                       unsigned short* __restrict__ dst) {
  __shared__ float t[32][33];
  const int n0 = blockIdx.x * 32, k0 = blockIdx.y * 32;
  const float* src;
  int nb, sN;
  if (n0 < 2048)      { src = wq; nb = n0;        sN = 2048; }
  else if (n0 < 2560) { src = wk; nb = n0 - 2048; sN = 512; }
  else                { src = wv; nb = n0 - 2560; sN = 512; }
  const int tx = threadIdx.x & 31, ty = threadIdx.x >> 5;  // ty 0..7
#pragma unroll
  for (int i = 0; i < 4; i++) {
    int k = k0 + ty + i * 8;
    t[ty + i * 8][tx] = src[(size_t)k * sN + nb + tx];
  }
  __syncthreads();
#pragma unroll
  for (int i = 0; i < 4; i++) {
    int n = n0 + ty + i * 8;
    dst[(size_t)n * 2048 + k0 + tx] = f2bf(t[tx][ty + i * 8]);
  }
}

// --------------------------------------------------- transpose fp32 [2048][N] -> bf16 [N][2048]
__global__ __launch_bounds__(256) void k_transpose_w(const float* __restrict__ src,
                                                     unsigned short* __restrict__ dst, int N) {
  __shared__ float t[32][33];
  const int n0 = blockIdx.x * 32, k0 = blockIdx.y * 32;
  const int tx = threadIdx.x & 31, ty = threadIdx.x >> 5;
#pragma unroll
  for (int i = 0; i < 4; i++) {
    int k = k0 + ty + i * 8;
    t[ty + i * 8][tx] = src[(size_t)k * N + n0 + tx];
  }
  __syncthreads();
#pragma unroll
  for (int i = 0; i < 4; i++) {
    int n = n0 + ty + i * 8;
    dst[(size_t)n * 2048 + k0 + tx] = f2bf(t[tx][ty + i * 8]);
  }
}

// ---------------------------------------------------------------- GEMM  C = A[M][K] * Bt[N][K]^T
// 256xBN tile, K in 32-col halves, 4 LDS slots per operand (depth-3 prefetch), 8 waves.
// T2 swizzle (conflicts=0 verified) + T3 phases + T4 counted vmcnt + T5 setprio.
// MODE: 1 = f32 plain output; 2 = QKV-fused (rope on Q/K cols, VT-transpose on V cols).
template <int MODE, int BN, int WM, int WN>
__global__ __launch_bounds__(512) void k_gemm8(const unsigned short* __restrict__ A,
                                               const unsigned short* __restrict__ Bt,
                                               void* __restrict__ Cp,
                                               unsigned short* __restrict__ vtp,
                                               const float* __restrict__ ctab,
                                               const float* __restrict__ stab,
                                               int M, int N, int K) {
  constexpr int BM = 256;
  constexpr int FM = BM / WM / 16;  // m-frags per wave
  constexpr int FN = BN / WN / 16;  // n-frags per wave
  constexpr int LA = BM * 4 / 512;  // A stage loads per thread per half
  constexpr int LB = BN * 4 / 512;  // B stage loads per thread per half
  constexpr int LH = LA + LB;
  __shared__ __align__(16) unsigned short As[4][BM * 32];
  __shared__ __align__(16) unsigned short Bs[4][BN * 32];

  const int nbx = N / BN;
  const int nwg = gridDim.x;
  int wg = blockIdx.x;
  wg = (wg & 7) * (nwg >> 3) + (wg >> 3);  // XCD swizzle (nwg % 8 == 0 here)
  const int bx = wg % nbx, by = wg / nbx;
  const int m0 = by << 8, n0 = bx * BN;
  const int tid = threadIdx.x;
  const int lane = tid & 63, wid = tid >> 6;
  const int wm = wid / WN, wn = wid % WN;
  const int l15 = lane & 15, kg = lane >> 4;
  const int H = K >> 5;   // 32-col halves
  const int NT = K >> 6;  // 64-col tiles

  auto stageA = [&](int h, int i) {
    const int u = i * 512 + tid;
    const int row = u >> 2, sl = u & 3;
    const int gc = ((sl ^ ((row >> 1) & 3)) << 3);
    load16_lds(&A[(size_t)(m0 + row) * K + (h << 5) + gc],
               &As[h & 3][(i * 512 + (tid & ~63)) * 8]);
  };
  auto stageB = [&](int h, int i) {
    const int u = i * 512 + tid;
    const int row = u >> 2, sl = u & 3;
    const int gc = ((sl ^ ((row >> 1) & 3)) << 3);
    load16_lds(&Bt[(size_t)(n0 + row) * K + (h << 5) + gc],
               &Bs[h & 3][(i * 512 + (tid & ~63)) * 8]);
  };
  auto lda = [&](int s, int r) {
    return *(const bf16x8*)&As[s][r * 32 + ((kg ^ ((r >> 1) & 3)) << 3)];
  };
  auto ldb = [&](int s, int r) {
    return *(const bf16x8*)&Bs[s][r * 32 + ((kg ^ ((r >> 1) & 3)) << 3)];
  };

#define VMCNT_C2(c)                                                   \
  if ((c) == 2)      asm volatile("s_waitcnt vmcnt(%0)" ::"n"(2 * LH) : "memory"); \
  else if ((c) == 1) asm volatile("s_waitcnt vmcnt(%0)" ::"n"(LH) : "memory");     \
  else               asm volatile("s_waitcnt vmcnt(0)" ::: "memory");

  const int rowA0 = wm * (BM / WM) + l15;
  const int rowB0 = wn * (BN / WN) + l15;

  bf16x8 af[FM / 2], bf[FN];
  f32x4 acc[FM][FN] = {};

  // prologue: stage halves 0,1,2; wait half 0
#pragma unroll
  for (int h = 0; h < 3; h++) {
    stageA(h, 0); stageA(h, 1);
    stageB(h, 0); if (LB > 1) stageB(h, 1);
  }
  asm volatile("s_waitcnt vmcnt(%0)" ::"n"(2 * LH) : "memory");
  __builtin_amdgcn_s_barrier();

  for (int t = 0; t < NT; t++) {
    const int s0 = (2 * t) & 3, s1 = (2 * t + 1) & 3;
    const int h3 = 2 * t + 3, h4 = 2 * t + 4;
    const bool v2 = (2 * t + 2) < H, v3 = h3 < H, v4 = h4 < H;

    // ---- P0: kc0, m-half 0
#pragma unroll
    for (int f = 0; f < FM / 2; f++) af[f] = lda(s0, rowA0 + f * 16);
#pragma unroll
    for (int g = 0; g < FN; g++) bf[g] = ldb(s0, rowB0 + g * 16);
    if (v3) { stageA(h3, 0); stageA(h3, 1); }
    __builtin_amdgcn_s_barrier();
    __builtin_amdgcn_s_setprio(1);
#pragma unroll
    for (int f = 0; f < FM / 2; f++)
#pragma unroll
      for (int g = 0; g < FN; g++) acc[f][g] = mfma16x16(af[f], bf[g], acc[f][g]);
    __builtin_amdgcn_s_setprio(0);

    // ---- P1: kc0, m-half 1 (reuse bf)
#pragma unroll
    for (int f = 0; f < FM / 2; f++) af[f] = lda(s0, rowA0 + (FM / 2 + f) * 16);
    if (v3) { stageB(h3, 0); if (LB > 1) stageB(h3, 1); }
    __builtin_amdgcn_s_barrier();
    __builtin_amdgcn_s_setprio(1);
#pragma unroll
    for (int f = 0; f < FM / 2; f++)
#pragma unroll
      for (int g = 0; g < FN; g++)
        acc[FM / 2 + f][g] = mfma16x16(af[f], bf[g], acc[FM / 2 + f][g]);
    __builtin_amdgcn_s_setprio(0);
    { const int c = (int)v2 + (int)v3; VMCNT_C2(c) }
    __builtin_amdgcn_s_barrier();  // half 2t+1 ready

    // ---- P2: kc1, m-half 0
#pragma unroll
    for (int f = 0; f < FM / 2; f++) af[f] = lda(s1, rowA0 + f * 16);
#pragma unroll
    for (int g = 0; g < FN; g++) bf[g] = ldb(s1, rowB0 + g * 16);
    if (v4) { stageA(h4, 0); stageA(h4, 1); }
    __builtin_amdgcn_s_barrier();
    __builtin_amdgcn_s_setprio(1);
#pragma unroll
    for (int f = 0; f < FM / 2; f++)
#pragma unroll
      for (int g = 0; g < FN; g++) acc[f][g] = mfma16x16(af[f], bf[g], acc[f][g]);
    __builtin_amdgcn_s_setprio(0);

    // ---- P3: kc1, m-half 1
#pragma unroll
    for (int f = 0; f < FM / 2; f++) af[f] = lda(s1, rowA0 + (FM / 2 + f) * 16);
    if (v4) { stageB(h4, 0); if (LB > 1) stageB(h4, 1); }
    __builtin_amdgcn_s_barrier();
    __builtin_amdgcn_s_setprio(1);
#pragma unroll
    for (int f = 0; f < FM / 2; f++)
#pragma unroll
      for (int g = 0; g < FN; g++)
        acc[FM / 2 + f][g] = mfma16x16(af[f], bf[g], acc[FM / 2 + f][g]);
    __builtin_amdgcn_s_setprio(0);
    { const int c = (int)v3 + (int)v4; VMCNT_C2(c) }
    __builtin_amdgcn_s_barrier();  // half 2t+2 ready
  }
#undef VMCNT_C2

  // epilogue: C layout col=l15, row=kg*4+j per 16x16 frag
  const int orow = m0 + wm * (BM / WM) + kg * 4;
  if (MODE == 1) {
#pragma unroll
    for (int fm = 0; fm < FM; fm++) {
#pragma unroll
      for (int fn = 0; fn < FN; fn++) {
        const int col = n0 + wn * (BN / WN) + fn * 16 + l15;
#pragma unroll
        for (int j = 0; j < 4; j++)
          ((float*)Cp)[(size_t)(orow + fm * 16 + j) * N + col] = acc[fm][fn][j];
      }
    }
  } else if (MODE == 2 && n0 >= 2560) {
    // V region: write VT[(b*8+kh)*64 + d][s] directly, 4 s-values packed per store
#pragma unroll
    for (int fm = 0; fm < FM; fm++) {
      const int row0 = orow + fm * 16;
      const int b = row0 >> 10, s0 = row0 & 1023;
#pragma unroll
      for (int fn = 0; fn < FN; fn++) {
        const int vcol = n0 + wn * (BN / WN) + fn * 16 + l15 - 2560;
        ushort4 ov;
        ov.x = f2bf(acc[fm][fn][0]); ov.y = f2bf(acc[fm][fn][1]);
        ov.z = f2bf(acc[fm][fn][2]); ov.w = f2bf(acc[fm][fn][3]);
        *(ushort4*)&vtp[((size_t)((b * 8 + (vcol >> 6)) * 64 + (vcol & 63))) * 1024 + s0] = ov;
      }
    }
  } else if (MODE == 2) {
    // Q/K region: apply RoPE in-register (partner value via shfl_xor(1)) and store bf16
    unsigned short* Cq = (unsigned short*)Cp;
#pragma unroll
    for (int fm = 0; fm < FM; fm++) {
#pragma unroll
      for (int fn = 0; fn < FN; fn++) {
        const int col = n0 + wn * (BN / WN) + fn * 16 + l15;
        const int pair = (col & 63) >> 1;
#pragma unroll
        for (int j = 0; j < 4; j++) {
          const int row = orow + fm * 16 + j;
          const int s = row & 1023;
          const float v = acc[fm][fn][j];
          const float pv = __shfl_xor(v, 1);
          const float c = ctab[s * 32 + pair], sn = stab[s * 32 + pair];
          const float outv = (col & 1) ? (pv * sn + v * c) : (v * c - pv * sn);
          Cq[(size_t)row * (size_t)N + col] = f2bf(outv);
        }
      }
    }
  }
}

// ---------------------------------------------------------------- flash attention (causal, GQA)
// Swapped-operand structure: sc = mfma(K,Q) -> S^T[k][q], q = l15 lane-local, so
// softmax max/sum are lane-local trees + 2 shfl (kg axis). PV also swapped:
// o = mfma(V^T, P) -> O^T[d][q]; rescale fac and 1/l are per-lane scalars.
// 4 waves share K/V LDS staging (double-buffered, XOR-swizzled, global_load_lds).
// LDS = 40960 B exactly -> 4 blocks/CU.
__global__ __launch_bounds__(256) void k_attn(const unsigned short* __restrict__ qkv,
                                              const unsigned short* __restrict__ vt,
                                              unsigned short* __restrict__ ao) {
  __shared__ __align__(16) unsigned short Ks[2][64 * 64];
  __shared__ __align__(16) unsigned short Vs[2][64 * 64];
  __shared__ __align__(16) unsigned short P[4][16][64];  // per-wave, k-XOR-swizzled

  const int bid = blockIdx.x;
  const int qt = 15 - (bid >> 7);
  const int hb = bid & 127;
  const int h = hb & 31, b = hb >> 5;
  const int q0 = qt << 6;
  const int wid = threadIdx.x >> 6, lane = threadIdx.x & 63;
  const int l15 = lane & 15, kg = lane >> 4;
  const int kh = h >> 2;
  const int qbase = b * 1024 + q0 + wid * 16;
  const int nt = qt + 1;
  const float NEGINF = -__builtin_inff();

  // Q fragments, pre-scaled by 1/sqrt(64) * log2(e) (softmax in exp2 domain)
  bf16x8 aq0, aq1;
  {
    const size_t qoff = (size_t)(qbase + l15) * 3072 + h * 64 + kg * 8;
    aq0 = *(const bf16x8*)&qkv[qoff];
    aq1 = *(const bf16x8*)&qkv[qoff + 32];
#pragma unroll
    for (int i = 0; i < 8; i++) {
      aq0[i] = (__bf16)((float)aq0[i] * 0.18033688011112042f);
      aq1[i] = (__bf16)((float)aq1[i] * 0.18033688011112042f);
    }
  }

  // staging geometry: lane l stages row (l>>3), 16B slot (l&7); source col is
  // inverse-XOR-swizzled so that the swizzled LDS read below sees linear data.
  const int l8 = lane >> 3;
  const int colel = ((lane & 7) ^ l8) * 8;  // element offset, pre-swizzled
  const size_t krowbase = (size_t)(b * 1024) * 3072 + 2048 + kh * 64 + colel;
  const size_t vrowbase = (size_t)((b * 8 + kh) * 64) * 1024 + colel;

  // prologue: stage tile 0
#pragma unroll
  for (int i = 0; i < 2; i++) {
    const int r = wid * 16 + i * 8 + l8;
    load16_lds(&qkv[krowbase + (size_t)r * 3072], &Ks[0][(wid * 16 + i * 8) * 64]);
    load16_lds(&vt[vrowbase + (size_t)r * 1024], &Vs[0][(wid * 16 + i * 8) * 64]);
  }
  asm volatile("s_waitcnt vmcnt(0)" ::: "memory");
  __builtin_amdgcn_s_barrier();

  f32x4 o[4] = {};
  float mrow = NEGINF;  // running max for q = l15 (replicated across kg)
  float lrow = 0.f;     // running sum for q = l15

  const int swz = (l15 & 7) * 8;  // read-side XOR swizzle for K/V tiles (elements)
  const int psw = (l15 & 7) * 8;  // P k-swizzle (same form)

  for (int t = 0; t < nt; t++) {
    const int cur = t & 1;
    // prefetch next tile into the other buffer (stays in flight during compute)
    if (t + 1 < nt) {
      const size_t kv1 = (size_t)((t + 1) << 6);
#pragma unroll
      for (int i = 0; i < 2; i++) {
        const int r = wid * 16 + i * 8 + l8;
        load16_lds(&qkv[krowbase + (kv1 + r) * 3072], &Ks[cur ^ 1][(wid * 16 + i * 8) * 64]);
        load16_lds(&vt[vrowbase + (size_t)r * 1024 + kv1], &Vs[cur ^ 1][(wid * 16 + i * 8) * 64]);
      }
    }

    // QK^T (swapped): sc[ct] = K_frag * Q^T -> S^T[k = ct*16+kg*4+reg][q = l15]
    f32x4 sc[4] = {};
    __builtin_amdgcn_s_setprio(1);
#pragma unroll
    for (int ct = 0; ct < 4; ct++) {
      const unsigned short* kr = &Ks[cur][(ct * 16 + l15) * 64];
      bf16x8 bk0 = *(const bf16x8*)&kr[(kg * 8) ^ swz];
      bf16x8 bk1 = *(const bf16x8*)&kr[(kg * 8 + 32) ^ swz];
      sc[ct] = mfma16x16(bk0, aq0, sc[ct]);
      sc[ct] = mfma16x16(bk1, aq1, sc[ct]);
    }
    __builtin_amdgcn_s_setprio(0);

    // scores for this lane's q (= l15): 16 values over k
    float p[4][4];
    if (t == qt) {
      const int qloc = wid * 16 + l15;  // local q within 64-tile (kv0 == q0)
#pragma unroll
      for (int ct = 0; ct < 4; ct++)
#pragma unroll
        for (int reg = 0; reg < 4; reg++) {
          const int kloc = ct * 16 + kg * 4 + reg;
          p[ct][reg] = (kloc > qloc) ? NEGINF : sc[ct][reg];
        }
    } else {
#pragma unroll
      for (int ct = 0; ct < 4; ct++)
#pragma unroll
        for (int reg = 0; reg < 4; reg++) p[ct][reg] = sc[ct][reg];
    }

    // tile max: lane-local tree + 2 shfl over kg axis
    float rm = NEGINF;
#pragma unroll
    for (int ct = 0; ct < 4; ct++)
      rm = fmaxf(rm, fmaxf(fmaxf(p[ct][0], p[ct][1]), fmaxf(p[ct][2], p[ct][3])));
    rm = fmaxf(rm, __shfl_xor(rm, 16));
    rm = fmaxf(rm, __shfl_xor(rm, 32));

    const float mnew = fmaxf(mrow, rm);
    const float fac = exp2f(mrow - mnew);  // -inf - finite -> 0
    float rs = 0.f;
#pragma unroll
    for (int ct = 0; ct < 4; ct++)
#pragma unroll
      for (int reg = 0; reg < 4; reg++) {
        const float e = exp2f(p[ct][reg] - mnew);
        p[ct][reg] = e;
        rs += e;
      }
    rs += __shfl_xor(rs, 16);
    rs += __shfl_xor(rs, 32);
    lrow = lrow * fac + rs;
    mrow = mnew;
#pragma unroll
    for (int ct = 0; ct < 4; ct++) {
      o[ct][0] *= fac; o[ct][1] *= fac; o[ct][2] *= fac; o[ct][3] *= fac;
    }

    // P[q=l15][k] to wave-private LDS, packed 4 regs = 8B, k-swizzled
#pragma unroll
    for (int ct = 0; ct < 4; ct++) {
      ushort4 pk;
      pk.x = f2bf(p[ct][0]); pk.y = f2bf(p[ct][1]);
      pk.z = f2bf(p[ct][2]); pk.w = f2bf(p[ct][3]);
      *(ushort4*)&P[wid][l15][(ct * 16 + kg * 4) ^ psw] = pk;
    }

    // read P row l15 as B-fragments (contiguous, swizzle preserved at 8-elem blocks)
    bf16x8 ap0 = *(const bf16x8*)&P[wid][l15][(kg * 8) ^ psw];
    bf16x8 ap1 = *(const bf16x8*)&P[wid][l15][(32 + kg * 8) ^ psw];

    // PV (swapped): o[ct] = V^T_frag * P -> O^T[d = ct*16+kg*4+reg][q = l15]
    __builtin_amdgcn_s_setprio(1);
#pragma unroll
    for (int ct = 0; ct < 4; ct++) {
      const unsigned short* vr = &Vs[cur][(ct * 16 + l15) * 64];
      bf16x8 bv0 = *(const bf16x8*)&vr[(kg * 8) ^ swz];
      bf16x8 bv1 = *(const bf16x8*)&vr[(kg * 8 + 32) ^ swz];
      o[ct] = mfma16x16(bv0, ap0, o[ct]);
      o[ct] = mfma16x16(bv1, ap1, o[ct]);
    }
    __builtin_amdgcn_s_setprio(0);

    // next tile's staging must be complete, and all waves done reading cur,
    // before cur^1 is consumed / cur is overwritten next iteration.
    asm volatile("s_waitcnt vmcnt(0)" ::: "memory");
    __builtin_amdgcn_s_barrier();
  }

  // epilogue: O^T[d][q]: lane writes q = qbase+l15, d = ct*16+kg*4+reg (packed 8B)
  const float rl = 1.0f / lrow;
  const size_t obase = (size_t)(qbase + l15) * 2048 + h * 64;
#pragma unroll
  for (int ct = 0; ct < 4; ct++) {
    ushort4 ov;
    ov.x = f2bf(o[ct][0] * rl); ov.y = f2bf(o[ct][1] * rl);
    ov.z = f2bf(o[ct][2] * rl); ov.w = f2bf(o[ct][3] * rl);
    *(ushort4*)&ao[obase + ct * 16 + kg * 4] = ov;
  }
}

// ---------------------------------------------------------------- launcher
extern "C" void kernel_launch(void* const* d_in, const int* in_sizes, int n_in,
                              void* d_out, int out_size, void* d_ws, size_t ws_size,
                              hipStream_t stream) {
  const float* x    = (const float*)d_in[0];
  const float* pcos = (const float*)d_in[1];
  const float* psin = (const float*)d_in[2];
  const float* wq   = (const float*)d_in[3];
  const float* wk   = (const float*)d_in[4];
  const float* wv   = (const float*)d_in[5];
  const float* wo   = (const float*)d_in[6];

  char* ws = (char*)d_ws;
  unsigned short* XB  = (unsigned short*)(ws);              // 4096x2048 bf16 (x, later attn-out)
  unsigned short* WT  = (unsigned short*)(ws + 16777216);   // 3072x2048 bf16 (wq|wk|wv)^T
  unsigned short* WOT = (unsigned short*)(ws + 29360128);   // 2048x2048 bf16 wo^T
  unsigned short* QKV = (unsigned short*)(ws + 37748736);   // 4096x3072 bf16 (V region unused)
  unsigned short* VT  = (unsigned short*)(ws + 62914560);   // (4*8*64)x1024 bf16
  // total 64 MiB

  k_convert_x<<<8192, 256, 0, stream>>>(x, XB, 8388608);
  k_transpose_qkv<<<dim3(96, 64), 256, 0, stream>>>(wq, wk, wv, WT);
  k_transpose_w<<<dim3(64, 64), 256, 0, stream>>>(wo, WOT, 2048);

  // QKV GEMM with fused RoPE (Q/K) + fused V->VT transpose
  k_gemm8<2, 256, 2, 4><<<192, 512, 0, stream>>>(XB, WT, QKV, VT, pcos, psin,
                                                 4096, 3072, 2048);
  k_attn<<<2048, 256, 0, stream>>>(QKV, VT, XB);
  k_gemm8<1, 128, 4, 2><<<256, 512, 0, stream>>>(XB, WOT, d_out, nullptr, nullptr, nullptr,
                                                 4096, 2048, 2048);
}